// Round 1
// baseline (1042.389 us; speedup 1.0000x reference)
//
#include <hip/hip_runtime.h>
#include <stdint.h>

#define N_TOK 8192
#define DDIM 1024
#define FDIM 4096
#define NEXP 8
#define MAX_BLOCKS 137
#define MAX_ROWS (MAX_BLOCKS * 128)

typedef _Float16 half8 __attribute__((ext_vector_type(8)));
typedef float floatx4 __attribute__((ext_vector_type(4)));

__device__ __forceinline__ void gload_lds16(const void* g, void* l) {
  __builtin_amdgcn_global_load_lds(
      (const __attribute__((address_space(1))) unsigned int*)(uintptr_t)g,
      (__attribute__((address_space(3))) unsigned int*)(uint32_t)(uintptr_t)l,
      16, 0, 0);
}

// ---------------- weight convert + transpose (fp32 [R][C] -> fp16 [C][R]) ----
__global__ void conv_transpose(const float* __restrict__ src,
                               _Float16* __restrict__ dst, int R, int C) {
  __shared__ float t[32][33];
  int e = blockIdx.z;
  const float* s = src + (size_t)e * R * C;
  _Float16* d = dst + (size_t)e * R * C;
  int c0 = blockIdx.x * 32, r0 = blockIdx.y * 32;
  int tx = threadIdx.x, ty = threadIdx.y;
#pragma unroll
  for (int i = 0; i < 32; i += 8)
    t[ty + i][tx] = s[(size_t)(r0 + ty + i) * C + c0 + tx];
  __syncthreads();
#pragma unroll
  for (int i = 0; i < 32; i += 8)
    d[(size_t)(c0 + ty + i) * R + r0 + tx] = (_Float16)t[tx][ty + i];
}

// ---------------- router: logits, top-2, softmax(fp32), counts --------------
__global__ __launch_bounds__(256) void router_kernel(
    const float* __restrict__ x, const float* __restrict__ rw,
    int* __restrict__ tok_e, float* __restrict__ tok_w, int* __restrict__ meta) {
  __shared__ float srw[NEXP * DDIM];
  int tid = threadIdx.x;
  const float4* rw4 = (const float4*)rw;
  float4* srw4 = (float4*)srw;
#pragma unroll
  for (int i = 0; i < 8; ++i) srw4[tid + i * 256] = rw4[tid + i * 256];
  __syncthreads();

  int wv = tid >> 6, l = tid & 63;
  int t = blockIdx.x * 4 + wv;
  const float4* xr = (const float4*)(x + (size_t)t * DDIM + l * 16);
  float4 xv[4];
#pragma unroll
  for (int i = 0; i < 4; ++i) xv[i] = xr[i];

  float logit[NEXP];
#pragma unroll
  for (int e = 0; e < NEXP; ++e) {
    const float4* wr4 = (const float4*)(srw + e * DDIM + l * 16);
    float acc = 0.f;
#pragma unroll
    for (int i = 0; i < 4; ++i) {
      float4 w4 = wr4[i];
      acc += xv[i].x * w4.x + xv[i].y * w4.y + xv[i].z * w4.z + xv[i].w * w4.w;
    }
#pragma unroll
    for (int off = 32; off > 0; off >>= 1) acc += __shfl_xor(acc, off);
    logit[e] = acc;
  }
  if (l == 0) {
    int i1 = 0;
    float v1 = logit[0];
#pragma unroll
    for (int e = 1; e < NEXP; ++e)
      if (logit[e] > v1) { v1 = logit[e]; i1 = e; }
    int i2 = -1;
    float v2 = -1e30f;
#pragma unroll
    for (int e = 0; e < NEXP; ++e)
      if (e != i1 && logit[e] > v2) { v2 = logit[e]; i2 = e; }
    float ex = expf(v2 - v1);  // v2 <= v1
    float denom = 1.f + ex;
    tok_e[2 * t] = i1;
    tok_e[2 * t + 1] = i2;
    tok_w[2 * t] = 1.f / denom;
    tok_w[2 * t + 1] = ex / denom;
    atomicAdd(&meta[i1], 1);
    atomicAdd(&meta[i2], 1);
  }
}

// ---------------- offsets: padded segments + block->expert table ------------
__global__ void offsets_kernel(int* meta) {
  int* counts = meta;
  int* fill = meta + 8;
  int* seg = meta + 16;   // [9]
  int* be = meta + 32;    // [MAX_BLOCKS]
  int s = 0;
  for (int e = 0; e < NEXP; ++e) {
    seg[e] = s;
    fill[e] = s;
    s += (counts[e] + 127) & ~127;
  }
  seg[NEXP] = s;
  for (int b = 0; b < MAX_BLOCKS; ++b) {
    int ee = -1;
    int row = b * 128;
    for (int e = 0; e < NEXP; ++e)
      if (row >= seg[e] && row < seg[e + 1]) ee = e;
    be[b] = ee;
  }
}

// ---------------- gather: pair -> slot ---------------------------------------
__global__ void gather_kernel(const int* __restrict__ tok_e,
                              const float* __restrict__ tok_w, int* meta,
                              int* __restrict__ row_map, float* __restrict__ row_w) {
  int p = blockIdx.x * 256 + threadIdx.x;  // 0..16383
  int e = tok_e[p];
  int pos = atomicAdd(&meta[8 + e], 1);
  row_map[pos] = p >> 1;
  row_w[pos] = tok_w[p];
}

// ---------------- Xg fill: gather x rows as fp16 (zeros for pads) -----------
__global__ void xg_fill_kernel(const float* __restrict__ x,
                               const int* __restrict__ row_map,
                               _Float16* __restrict__ Xg) {
  int r = blockIdx.x, t = threadIdx.x;
  int n = row_map[r];
  half8 h = {0, 0, 0, 0, 0, 0, 0, 0};
  if (n >= 0) {
    const float4* s = (const float4*)(x + (size_t)n * DDIM + t * 8);
    float4 a = s[0], b = s[1];
    h[0] = (_Float16)a.x; h[1] = (_Float16)a.y;
    h[2] = (_Float16)a.z; h[3] = (_Float16)a.w;
    h[4] = (_Float16)b.x; h[5] = (_Float16)b.y;
    h[6] = (_Float16)b.z; h[7] = (_Float16)b.w;
  }
  *(half8*)(Xg + (size_t)r * DDIM + t * 8) = h;
}

// ---------------- grouped GEMM (A[M,K] x B^T[N,K]), 128x128x64 --------------
// EPI=0: gelu -> Hout fp16.  EPI=1: atomicAdd(out[token], w * val).
template <int EPI>
__global__ __launch_bounds__(256) void gemm_bt(
    const _Float16* __restrict__ A, const _Float16* __restrict__ Bbase,
    const int* __restrict__ be, int lda, int ldb, int K, long long b_estride,
    _Float16* __restrict__ Hout, int ldh, float* __restrict__ out,
    const int* __restrict__ row_map, const float* __restrict__ row_w) {
  int e = be[blockIdx.x];
  if (e < 0) return;
  const _Float16* Ab = A + (size_t)blockIdx.x * 128 * lda;
  const _Float16* Bb = Bbase + (size_t)e * b_estride + (size_t)blockIdx.y * 128 * ldb;

  __shared__ __align__(16) _Float16 sA[128 * 64];
  __shared__ __align__(16) _Float16 sB[128 * 64];

  int tid = threadIdx.x;
  int w = tid >> 6, l = tid & 63;
  int wr = (w >> 1) * 64, wc = (w & 1) * 64;

  floatx4 acc[4][4] = {};

  int r0 = (l >> 3), kc = (l & 7) * 8;
  for (int kt = 0; kt < K; kt += 64) {
    const _Float16* As = Ab + kt;
    const _Float16* Bs = Bb + kt;
#pragma unroll
    for (int it = 0; it < 4; ++it) {
      int c = it * 4 + w;       // 16 chunks of 8 rows (1KB each)
      int row = c * 8 + r0;
      gload_lds16(As + (size_t)row * lda + kc, (void*)(sA + c * 512));
      gload_lds16(Bs + (size_t)row * ldb + kc, (void*)(sB + c * 512));
    }
    __syncthreads();  // drains vmcnt before reads

    half8 af[2][4], bf[2][4];
#pragma unroll
    for (int kk = 0; kk < 2; ++kk) {
#pragma unroll
      for (int m = 0; m < 4; ++m) {
        af[kk][m] = *(const half8*)&sA[(wr + m * 16 + (l & 15)) * 64 + kk * 32 + (l >> 4) * 8];
        bf[kk][m] = *(const half8*)&sB[(wc + m * 16 + (l & 15)) * 64 + kk * 32 + (l >> 4) * 8];
      }
    }
#pragma unroll
    for (int kk = 0; kk < 2; ++kk)
#pragma unroll
      for (int m = 0; m < 4; ++m)
#pragma unroll
        for (int n = 0; n < 4; ++n)
          acc[m][n] = __builtin_amdgcn_mfma_f32_16x16x32_f16(af[kk][m], bf[kk][n], acc[m][n], 0, 0, 0);
    __syncthreads();  // before next stage overwrites LDS
  }

  if (EPI == 0) {
#pragma unroll
    for (int m = 0; m < 4; ++m) {
#pragma unroll
      for (int j = 0; j < 4; ++j) {
        size_t r = (size_t)blockIdx.x * 128 + wr + m * 16 + (l >> 4) * 4 + j;
        _Float16* hp = Hout + r * ldh + (size_t)blockIdx.y * 128 + wc + (l & 15);
#pragma unroll
        for (int n = 0; n < 4; ++n) {
          float v = acc[m][n][j];
          v = 0.5f * v * (1.0f + erff(v * 0.70710678118f));  // exact gelu
          hp[n * 16] = (_Float16)v;
        }
      }
    }
  } else {
#pragma unroll
    for (int m = 0; m < 4; ++m) {
#pragma unroll
      for (int j = 0; j < 4; ++j) {
        int r = blockIdx.x * 128 + wr + m * 16 + (l >> 4) * 4 + j;
        int tok = row_map[r];
        if (tok < 0) continue;
        float wgt = row_w[r];
        float* op = out + (size_t)tok * DDIM + (size_t)blockIdx.y * 128 + wc + (l & 15);
#pragma unroll
        for (int n = 0; n < 4; ++n) atomicAdd(op + n * 16, wgt * acc[m][n][j]);
      }
    }
  }
}

// ---------------- launch -----------------------------------------------------
extern "C" void kernel_launch(void* const* d_in, const int* in_sizes, int n_in,
                              void* d_out, int out_size, void* d_ws, size_t ws_size,
                              hipStream_t stream) {
  const float* x = (const float*)d_in[0];
  const float* rw = (const float*)d_in[1];
  const float* w1 = (const float*)d_in[2];
  const float* w2 = (const float*)d_in[3];
  float* out = (float*)d_out;

  char* base = (char*)d_ws;
  size_t off = 0;
  auto alloc = [&](size_t bytes) {
    void* p = base + off;
    off += (bytes + 255) & ~(size_t)255;
    return p;
  };
  _Float16* w1t = (_Float16*)alloc((size_t)NEXP * FDIM * DDIM * 2);
  _Float16* w2t = (_Float16*)alloc((size_t)NEXP * DDIM * FDIM * 2);
  _Float16* Xg = (_Float16*)alloc((size_t)MAX_ROWS * DDIM * 2);
  int* row_map = (int*)alloc(MAX_ROWS * 4);
  float* row_w = (float*)alloc(MAX_ROWS * 4);
  int* tok_e = (int*)alloc(N_TOK * 2 * 4);
  float* tok_w = (float*)alloc(N_TOK * 2 * 4);
  int* meta = (int*)alloc(1024);
  size_t fixed = off;

  // F-chunking so the H buffer fits the provided workspace.
  int NC = 1;
  while (NC < 16 && fixed + (size_t)MAX_ROWS * (FDIM / NC) * 2 > ws_size) NC *= 2;
  int Fc = FDIM / NC;
  _Float16* H = (_Float16*)alloc((size_t)MAX_ROWS * Fc * 2);

  hipMemsetAsync(out, 0, (size_t)N_TOK * DDIM * 4, stream);
  hipMemsetAsync(meta, 0, 64, stream);                 // counts + fill
  hipMemsetAsync(row_map, 0xFF, MAX_ROWS * 4, stream); // -1 sentinels

  conv_transpose<<<dim3(FDIM / 32, DDIM / 32, NEXP), dim3(32, 8), 0, stream>>>(w1, w1t, DDIM, FDIM);
  conv_transpose<<<dim3(DDIM / 32, FDIM / 32, NEXP), dim3(32, 8), 0, stream>>>(w2, w2t, FDIM, DDIM);
  router_kernel<<<N_TOK / 4, 256, 0, stream>>>(x, rw, tok_e, tok_w, meta);
  offsets_kernel<<<1, 1, 0, stream>>>(meta);
  gather_kernel<<<N_TOK * 2 / 256, 256, 0, stream>>>(tok_e, tok_w, meta, row_map, row_w);
  xg_fill_kernel<<<MAX_ROWS, 128, 0, stream>>>(x, row_map, Xg);

  const int* be = meta + 32;
  for (int c = 0; c < NC; ++c) {
    gemm_bt<0><<<dim3(MAX_BLOCKS, Fc / 128), 256, 0, stream>>>(
        Xg, w1t + (size_t)c * Fc * DDIM, be, DDIM, DDIM, DDIM,
        (long long)FDIM * DDIM, H, Fc, nullptr, nullptr, nullptr);
    gemm_bt<1><<<dim3(MAX_BLOCKS, DDIM / 128), 256, 0, stream>>>(
        H, w2t + (size_t)c * Fc, be, Fc, FDIM, Fc,
        (long long)DDIM * FDIM, nullptr, 0, out, row_map, row_w);
  }
}

// Round 2
// 1041.672 us; speedup vs baseline: 1.0007x; 1.0007x over previous
//
#include <hip/hip_runtime.h>
#include <stdint.h>

#define N_TOK 8192
#define DDIM 1024
#define FDIM 4096
#define NEXP 8
#define MAX_BLOCKS 137
#define MAX_ROWS (MAX_BLOCKS * 128)

typedef _Float16 half8 __attribute__((ext_vector_type(8)));
typedef float floatx4 __attribute__((ext_vector_type(4)));

__device__ __forceinline__ void gload_lds16(const void* g, void* l) {
  __builtin_amdgcn_global_load_lds(
      (const __attribute__((address_space(1))) unsigned int*)(uintptr_t)g,
      (__attribute__((address_space(3))) unsigned int*)(uint32_t)(uintptr_t)l,
      16, 0, 0);
}

// ---------------- weight convert + transpose (fp32 [R][C] -> fp16 [C][R]) ----
__global__ void conv_transpose(const float* __restrict__ src,
                               _Float16* __restrict__ dst, int R, int C) {
  __shared__ float t[32][33];
  int e = blockIdx.z;
  const float* s = src + (size_t)e * R * C;
  _Float16* d = dst + (size_t)e * R * C;
  int c0 = blockIdx.x * 32, r0 = blockIdx.y * 32;
  int tx = threadIdx.x, ty = threadIdx.y;
#pragma unroll
  for (int i = 0; i < 32; i += 8)
    t[ty + i][tx] = s[(size_t)(r0 + ty + i) * C + c0 + tx];
  __syncthreads();
#pragma unroll
  for (int i = 0; i < 32; i += 8)
    d[(size_t)(c0 + ty + i) * R + r0 + tx] = (_Float16)t[tx][ty + i];
}

// ---------------- router: logits, top-2, softmax(fp32), counts --------------
__global__ __launch_bounds__(256) void router_kernel(
    const float* __restrict__ x, const float* __restrict__ rw,
    int* __restrict__ tok_e, float* __restrict__ tok_w, int* __restrict__ meta) {
  __shared__ float srw[NEXP * DDIM];
  int tid = threadIdx.x;
  const float4* rw4 = (const float4*)rw;
  float4* srw4 = (float4*)srw;
#pragma unroll
  for (int i = 0; i < 8; ++i) srw4[tid + i * 256] = rw4[tid + i * 256];
  __syncthreads();

  int wv = tid >> 6, l = tid & 63;
  int t = blockIdx.x * 4 + wv;
  const float4* xr = (const float4*)(x + (size_t)t * DDIM + l * 16);
  float4 xv[4];
#pragma unroll
  for (int i = 0; i < 4; ++i) xv[i] = xr[i];

  float logit[NEXP];
#pragma unroll
  for (int e = 0; e < NEXP; ++e) {
    const float4* wr4 = (const float4*)(srw + e * DDIM + l * 16);
    float acc = 0.f;
#pragma unroll
    for (int i = 0; i < 4; ++i) {
      float4 w4 = wr4[i];
      acc += xv[i].x * w4.x + xv[i].y * w4.y + xv[i].z * w4.z + xv[i].w * w4.w;
    }
#pragma unroll
    for (int off = 32; off > 0; off >>= 1) acc += __shfl_xor(acc, off);
    logit[e] = acc;
  }
  if (l == 0) {
    int i1 = 0;
    float v1 = logit[0];
#pragma unroll
    for (int e = 1; e < NEXP; ++e)
      if (logit[e] > v1) { v1 = logit[e]; i1 = e; }
    int i2 = -1;
    float v2 = -1e30f;
#pragma unroll
    for (int e = 0; e < NEXP; ++e)
      if (e != i1 && logit[e] > v2) { v2 = logit[e]; i2 = e; }
    float ex = expf(v2 - v1);  // v2 <= v1
    float denom = 1.f + ex;
    tok_e[2 * t] = i1;
    tok_e[2 * t + 1] = i2;
    tok_w[2 * t] = 1.f / denom;
    tok_w[2 * t + 1] = ex / denom;
    atomicAdd(&meta[i1], 1);
    atomicAdd(&meta[i2], 1);
  }
}

// ---------------- offsets: padded segments + block->expert table ------------
__global__ void offsets_kernel(int* meta) {
  int* counts = meta;
  int* fill = meta + 8;
  int* seg = meta + 16;   // [9]
  int* be = meta + 32;    // [MAX_BLOCKS]
  int s = 0;
  for (int e = 0; e < NEXP; ++e) {
    seg[e] = s;
    fill[e] = s;
    s += (counts[e] + 127) & ~127;
  }
  seg[NEXP] = s;
  for (int b = 0; b < MAX_BLOCKS; ++b) {
    int ee = -1;
    int row = b * 128;
    for (int e = 0; e < NEXP; ++e)
      if (row >= seg[e] && row < seg[e + 1]) ee = e;
    be[b] = ee;
  }
}

// ---------------- gather: pair -> slot ---------------------------------------
__global__ void gather_kernel(const int* __restrict__ tok_e,
                              const float* __restrict__ tok_w, int* meta,
                              int* __restrict__ row_map, float* __restrict__ row_w) {
  int p = blockIdx.x * 256 + threadIdx.x;  // 0..16383
  int e = tok_e[p];
  int pos = atomicAdd(&meta[8 + e], 1);
  row_map[pos] = p >> 1;
  row_w[pos] = tok_w[p];
}

// ---------------- Xg fill: gather x rows as fp16 (zeros for pads) -----------
__global__ void xg_fill_kernel(const float* __restrict__ x,
                               const int* __restrict__ row_map,
                               _Float16* __restrict__ Xg) {
  int r = blockIdx.x, t = threadIdx.x;
  int n = row_map[r];
  half8 h = {0, 0, 0, 0, 0, 0, 0, 0};
  if (n >= 0) {
    const float4* s = (const float4*)(x + (size_t)n * DDIM + t * 8);
    float4 a = s[0], b = s[1];
    h[0] = (_Float16)a.x; h[1] = (_Float16)a.y;
    h[2] = (_Float16)a.z; h[3] = (_Float16)a.w;
    h[4] = (_Float16)b.x; h[5] = (_Float16)b.y;
    h[6] = (_Float16)b.z; h[7] = (_Float16)b.w;
  }
  *(half8*)(Xg + (size_t)r * DDIM + t * 8) = h;
}

// ---------------- grouped GEMM (A[M,K] x B^T[N,K]), 128x128x64 --------------
// EPI=0: gelu -> Hout fp16.  EPI=1: atomicAdd(out[token], w * val).
template <int EPI>
__global__ __launch_bounds__(256) void gemm_bt(
    const _Float16* __restrict__ A, const _Float16* __restrict__ Bbase,
    const int* __restrict__ be, int lda, int ldb, int K, long long b_estride,
    _Float16* __restrict__ Hout, int ldh, float* __restrict__ out,
    const int* __restrict__ row_map, const float* __restrict__ row_w) {
  int e = be[blockIdx.x];
  if (e < 0) return;
  const _Float16* Ab = A + (size_t)blockIdx.x * 128 * lda;
  const _Float16* Bb = Bbase + (size_t)e * b_estride + (size_t)blockIdx.y * 128 * ldb;

  __shared__ __align__(16) _Float16 sA[128 * 64];
  __shared__ __align__(16) _Float16 sB[128 * 64];

  int tid = threadIdx.x;
  int w = tid >> 6, l = tid & 63;
  int wr = (w >> 1) * 64, wc = (w & 1) * 64;

  floatx4 acc[4][4] = {};

  int r0 = (l >> 3), kc = (l & 7) * 8;
  for (int kt = 0; kt < K; kt += 64) {
    const _Float16* As = Ab + kt;
    const _Float16* Bs = Bb + kt;
#pragma unroll
    for (int it = 0; it < 4; ++it) {
      int c = it * 4 + w;       // 16 chunks of 8 rows (1KB each)
      int row = c * 8 + r0;
      gload_lds16(As + (size_t)row * lda + kc, (void*)(sA + c * 512));
      gload_lds16(Bs + (size_t)row * ldb + kc, (void*)(sB + c * 512));
    }
    __syncthreads();  // drains vmcnt before reads

    half8 af[2][4], bf[2][4];
#pragma unroll
    for (int kk = 0; kk < 2; ++kk) {
#pragma unroll
      for (int m = 0; m < 4; ++m) {
        af[kk][m] = *(const half8*)&sA[(wr + m * 16 + (l & 15)) * 64 + kk * 32 + (l >> 4) * 8];
        bf[kk][m] = *(const half8*)&sB[(wc + m * 16 + (l & 15)) * 64 + kk * 32 + (l >> 4) * 8];
      }
    }
#pragma unroll
    for (int kk = 0; kk < 2; ++kk)
#pragma unroll
      for (int m = 0; m < 4; ++m)
#pragma unroll
        for (int n = 0; n < 4; ++n)
          acc[m][n] = __builtin_amdgcn_mfma_f32_16x16x32_f16(af[kk][m], bf[kk][n], acc[m][n], 0, 0, 0);
    __syncthreads();  // before next stage overwrites LDS
  }

  if (EPI == 0) {
#pragma unroll
    for (int m = 0; m < 4; ++m) {
#pragma unroll
      for (int j = 0; j < 4; ++j) {
        size_t r = (size_t)blockIdx.x * 128 + wr + m * 16 + (l >> 4) * 4 + j;
        _Float16* hp = Hout + r * ldh + (size_t)blockIdx.y * 128 + wc + (l & 15);
#pragma unroll
        for (int n = 0; n < 4; ++n) {
          float v = acc[m][n][j];
          v = 0.5f * v * (1.0f + erff(v * 0.70710678118f));  // exact gelu
          hp[n * 16] = (_Float16)v;
        }
      }
    }
  } else {
#pragma unroll
    for (int m = 0; m < 4; ++m) {
#pragma unroll
      for (int j = 0; j < 4; ++j) {
        int r = blockIdx.x * 128 + wr + m * 16 + (l >> 4) * 4 + j;
        int tok = row_map[r];
        if (tok < 0) continue;
        float wgt = row_w[r];
        float* op = out + (size_t)tok * DDIM + (size_t)blockIdx.y * 128 + wc + (l & 15);
#pragma unroll
        for (int n = 0; n < 4; ++n) atomicAdd(op + n * 16, wgt * acc[m][n][j]);
      }
    }
  }
}

// ---------------- launch -----------------------------------------------------
extern "C" void kernel_launch(void* const* d_in, const int* in_sizes, int n_in,
                              void* d_out, int out_size, void* d_ws, size_t ws_size,
                              hipStream_t stream) {
  const float* x = (const float*)d_in[0];
  const float* rw = (const float*)d_in[1];
  const float* w1 = (const float*)d_in[2];
  const float* w2 = (const float*)d_in[3];
  float* out = (float*)d_out;

  char* base = (char*)d_ws;
  size_t off = 0;
  auto alloc = [&](size_t bytes) {
    void* p = base + off;
    off += (bytes + 255) & ~(size_t)255;
    return p;
  };
  _Float16* w1t = (_Float16*)alloc((size_t)NEXP * FDIM * DDIM * 2);
  _Float16* w2t = (_Float16*)alloc((size_t)NEXP * DDIM * FDIM * 2);
  _Float16* Xg = (_Float16*)alloc((size_t)MAX_ROWS * DDIM * 2);
  int* row_map = (int*)alloc(MAX_ROWS * 4);
  float* row_w = (float*)alloc(MAX_ROWS * 4);
  int* tok_e = (int*)alloc(N_TOK * 2 * 4);
  float* tok_w = (float*)alloc(N_TOK * 2 * 4);
  int* meta = (int*)alloc(1024);
  size_t fixed = off;

  // F-chunking so the H buffer fits the provided workspace.
  int NC = 1;
  while (NC < 16 && fixed + (size_t)MAX_ROWS * (FDIM / NC) * 2 > ws_size) NC *= 2;
  int Fc = FDIM / NC;
  _Float16* H = (_Float16*)alloc((size_t)MAX_ROWS * Fc * 2);

  hipMemsetAsync(out, 0, (size_t)N_TOK * DDIM * 4, stream);
  hipMemsetAsync(meta, 0, 64, stream);                 // counts + fill
  hipMemsetAsync(row_map, 0xFF, MAX_ROWS * 4, stream); // -1 sentinels

  conv_transpose<<<dim3(FDIM / 32, DDIM / 32, NEXP), dim3(32, 8), 0, stream>>>(w1, w1t, DDIM, FDIM);
  conv_transpose<<<dim3(DDIM / 32, FDIM / 32, NEXP), dim3(32, 8), 0, stream>>>(w2, w2t, FDIM, DDIM);
  router_kernel<<<N_TOK / 4, 256, 0, stream>>>(x, rw, tok_e, tok_w, meta);
  offsets_kernel<<<1, 1, 0, stream>>>(meta);
  gather_kernel<<<N_TOK * 2 / 256, 256, 0, stream>>>(tok_e, tok_w, meta, row_map, row_w);
  xg_fill_kernel<<<MAX_ROWS, 128, 0, stream>>>(x, row_map, Xg);

  const int* be = meta + 32;
  for (int c = 0; c < NC; ++c) {
    gemm_bt<0><<<dim3(MAX_BLOCKS, Fc / 128), 256, 0, stream>>>(
        Xg, w1t + (size_t)c * Fc * DDIM, be, DDIM, DDIM, DDIM,
        (long long)FDIM * DDIM, H, Fc, nullptr, nullptr, nullptr);
    gemm_bt<1><<<dim3(MAX_BLOCKS, DDIM / 128), 256, 0, stream>>>(
        H, w2t + (size_t)c * Fc, be, Fc, FDIM, Fc,
        (long long)DDIM * FDIM, nullptr, 0, out, row_map, row_w);
  }
}

// Round 3
// 1040.784 us; speedup vs baseline: 1.0015x; 1.0009x over previous
//
#include <hip/hip_runtime.h>
#include <stdint.h>

#define N_TOK 8192
#define DDIM 1024
#define FDIM 4096
#define NEXP 8
#define MAX_BLOCKS 137
#define MAX_ROWS (MAX_BLOCKS * 128)

typedef _Float16 half8 __attribute__((ext_vector_type(8)));
typedef float floatx4 __attribute__((ext_vector_type(4)));

__device__ __forceinline__ void gload_lds16(const void* g, void* l) {
  __builtin_amdgcn_global_load_lds(
      (const __attribute__((address_space(1))) unsigned int*)(uintptr_t)g,
      (__attribute__((address_space(3))) unsigned int*)(uint32_t)(uintptr_t)l,
      16, 0, 0);
}

// ---------------- weight convert + transpose (fp32 [R][C] -> fp16 [C][R]) ----
__global__ void conv_transpose(const float* __restrict__ src,
                               _Float16* __restrict__ dst, int R, int C) {
  __shared__ float t[32][33];
  int e = blockIdx.z;
  const float* s = src + (size_t)e * R * C;
  _Float16* d = dst + (size_t)e * R * C;
  int c0 = blockIdx.x * 32, r0 = blockIdx.y * 32;
  int tx = threadIdx.x, ty = threadIdx.y;
#pragma unroll
  for (int i = 0; i < 32; i += 8)
    t[ty + i][tx] = s[(size_t)(r0 + ty + i) * C + c0 + tx];
  __syncthreads();
#pragma unroll
  for (int i = 0; i < 32; i += 8)
    d[(size_t)(c0 + ty + i) * R + r0 + tx] = (_Float16)t[tx][ty + i];
}

// ---------------- router: logits, top-2, softmax(fp32), counts --------------
__global__ __launch_bounds__(256) void router_kernel(
    const float* __restrict__ x, const float* __restrict__ rw,
    int* __restrict__ tok_e, float* __restrict__ tok_w, int* __restrict__ meta) {
  __shared__ float srw[NEXP * DDIM];
  int tid = threadIdx.x;
  const float4* rw4 = (const float4*)rw;
  float4* srw4 = (float4*)srw;
#pragma unroll
  for (int i = 0; i < 8; ++i) srw4[tid + i * 256] = rw4[tid + i * 256];
  __syncthreads();

  int wv = tid >> 6, l = tid & 63;
  int t = blockIdx.x * 4 + wv;
  const float4* xr = (const float4*)(x + (size_t)t * DDIM + l * 16);
  float4 xv[4];
#pragma unroll
  for (int i = 0; i < 4; ++i) xv[i] = xr[i];

  float logit[NEXP];
#pragma unroll
  for (int e = 0; e < NEXP; ++e) {
    const float4* wr4 = (const float4*)(srw + e * DDIM + l * 16);
    float acc = 0.f;
#pragma unroll
    for (int i = 0; i < 4; ++i) {
      float4 w4 = wr4[i];
      acc += xv[i].x * w4.x + xv[i].y * w4.y + xv[i].z * w4.z + xv[i].w * w4.w;
    }
#pragma unroll
    for (int off = 32; off > 0; off >>= 1) acc += __shfl_xor(acc, off);
    logit[e] = acc;
  }
  if (l == 0) {
    int i1 = 0;
    float v1 = logit[0];
#pragma unroll
    for (int e = 1; e < NEXP; ++e)
      if (logit[e] > v1) { v1 = logit[e]; i1 = e; }
    int i2 = -1;
    float v2 = -1e30f;
#pragma unroll
    for (int e = 0; e < NEXP; ++e)
      if (e != i1 && logit[e] > v2) { v2 = logit[e]; i2 = e; }
    float ex = expf(v2 - v1);  // v2 <= v1
    float denom = 1.f + ex;
    tok_e[2 * t] = i1;
    tok_e[2 * t + 1] = i2;
    tok_w[2 * t] = 1.f / denom;
    tok_w[2 * t + 1] = ex / denom;
    atomicAdd(&meta[i1], 1);
    atomicAdd(&meta[i2], 1);
  }
}

// ---------------- offsets: padded segments + block->expert table ------------
__global__ void offsets_kernel(int* meta) {
  int* counts = meta;
  int* fill = meta + 8;
  int* seg = meta + 16;   // [9]
  int* be = meta + 32;    // [MAX_BLOCKS]
  int s = 0;
  for (int e = 0; e < NEXP; ++e) {
    seg[e] = s;
    fill[e] = s;
    s += (counts[e] + 127) & ~127;
  }
  seg[NEXP] = s;
  for (int b = 0; b < MAX_BLOCKS; ++b) {
    int ee = -1;
    int row = b * 128;
    for (int e = 0; e < NEXP; ++e)
      if (row >= seg[e] && row < seg[e + 1]) ee = e;
    be[b] = ee;
  }
}

// ---------------- gather: pair -> slot ---------------------------------------
__global__ void gather_kernel(const int* __restrict__ tok_e,
                              const float* __restrict__ tok_w, int* meta,
                              int* __restrict__ row_map, float* __restrict__ row_w) {
  int p = blockIdx.x * 256 + threadIdx.x;  // 0..16383
  int e = tok_e[p];
  int pos = atomicAdd(&meta[8 + e], 1);
  row_map[pos] = p >> 1;
  row_w[pos] = tok_w[p];
}

// ---------------- Xg fill: gather x rows as fp16 (zeros for pads) -----------
__global__ void xg_fill_kernel(const float* __restrict__ x,
                               const int* __restrict__ row_map,
                               _Float16* __restrict__ Xg) {
  int r = blockIdx.x, t = threadIdx.x;
  int n = row_map[r];
  half8 h = {0, 0, 0, 0, 0, 0, 0, 0};
  if (n >= 0) {
    const float4* s = (const float4*)(x + (size_t)n * DDIM + t * 8);
    float4 a = s[0], b = s[1];
    h[0] = (_Float16)a.x; h[1] = (_Float16)a.y;
    h[2] = (_Float16)a.z; h[3] = (_Float16)a.w;
    h[4] = (_Float16)b.x; h[5] = (_Float16)b.y;
    h[6] = (_Float16)b.z; h[7] = (_Float16)b.w;
  }
  *(half8*)(Xg + (size_t)r * DDIM + t * 8) = h;
}

// ---------------- grouped GEMM (A[M,K] x B^T[N,K]), 128x128x64 --------------
// EPI=0: gelu -> Hout fp16.  EPI=1: atomicAdd(out[token], w * val).
template <int EPI>
__global__ __launch_bounds__(256) void gemm_bt(
    const _Float16* __restrict__ A, const _Float16* __restrict__ Bbase,
    const int* __restrict__ be, int lda, int ldb, int K, long long b_estride,
    _Float16* __restrict__ Hout, int ldh, float* __restrict__ out,
    const int* __restrict__ row_map, const float* __restrict__ row_w) {
  int e = be[blockIdx.x];
  if (e < 0) return;
  const _Float16* Ab = A + (size_t)blockIdx.x * 128 * lda;
  const _Float16* Bb = Bbase + (size_t)e * b_estride + (size_t)blockIdx.y * 128 * ldb;

  __shared__ __align__(16) _Float16 sA[128 * 64];
  __shared__ __align__(16) _Float16 sB[128 * 64];

  int tid = threadIdx.x;
  int w = tid >> 6, l = tid & 63;
  int wr = (w >> 1) * 64, wc = (w & 1) * 64;

  floatx4 acc[4][4] = {};

  int r0 = (l >> 3), kc = (l & 7) * 8;
  for (int kt = 0; kt < K; kt += 64) {
    const _Float16* As = Ab + kt;
    const _Float16* Bs = Bb + kt;
#pragma unroll
    for (int it = 0; it < 4; ++it) {
      int c = it * 4 + w;       // 16 chunks of 8 rows (1KB each)
      int row = c * 8 + r0;
      gload_lds16(As + (size_t)row * lda + kc, (void*)(sA + c * 512));
      gload_lds16(Bs + (size_t)row * ldb + kc, (void*)(sB + c * 512));
    }
    __syncthreads();  // drains vmcnt before reads

    half8 af[2][4], bf[2][4];
#pragma unroll
    for (int kk = 0; kk < 2; ++kk) {
#pragma unroll
      for (int m = 0; m < 4; ++m) {
        af[kk][m] = *(const half8*)&sA[(wr + m * 16 + (l & 15)) * 64 + kk * 32 + (l >> 4) * 8];
        bf[kk][m] = *(const half8*)&sB[(wc + m * 16 + (l & 15)) * 64 + kk * 32 + (l >> 4) * 8];
      }
    }
#pragma unroll
    for (int kk = 0; kk < 2; ++kk)
#pragma unroll
      for (int m = 0; m < 4; ++m)
#pragma unroll
        for (int n = 0; n < 4; ++n)
          acc[m][n] = __builtin_amdgcn_mfma_f32_16x16x32_f16(af[kk][m], bf[kk][n], acc[m][n], 0, 0, 0);
    __syncthreads();  // before next stage overwrites LDS
  }

  if (EPI == 0) {
#pragma unroll
    for (int m = 0; m < 4; ++m) {
#pragma unroll
      for (int j = 0; j < 4; ++j) {
        size_t r = (size_t)blockIdx.x * 128 + wr + m * 16 + (l >> 4) * 4 + j;
        _Float16* hp = Hout + r * ldh + (size_t)blockIdx.y * 128 + wc + (l & 15);
#pragma unroll
        for (int n = 0; n < 4; ++n) {
          float v = acc[m][n][j];
          v = 0.5f * v * (1.0f + erff(v * 0.70710678118f));  // exact gelu
          hp[n * 16] = (_Float16)v;
        }
      }
    }
  } else {
#pragma unroll
    for (int m = 0; m < 4; ++m) {
#pragma unroll
      for (int j = 0; j < 4; ++j) {
        int r = blockIdx.x * 128 + wr + m * 16 + (l >> 4) * 4 + j;
        int tok = row_map[r];
        if (tok < 0) continue;
        float wgt = row_w[r];
        float* op = out + (size_t)tok * DDIM + (size_t)blockIdx.y * 128 + wc + (l & 15);
#pragma unroll
        for (int n = 0; n < 4; ++n) atomicAdd(op + n * 16, wgt * acc[m][n][j]);
      }
    }
  }
}

// ---------------- launch -----------------------------------------------------
extern "C" void kernel_launch(void* const* d_in, const int* in_sizes, int n_in,
                              void* d_out, int out_size, void* d_ws, size_t ws_size,
                              hipStream_t stream) {
  const float* x = (const float*)d_in[0];
  const float* rw = (const float*)d_in[1];
  const float* w1 = (const float*)d_in[2];
  const float* w2 = (const float*)d_in[3];
  float* out = (float*)d_out;

  char* base = (char*)d_ws;
  size_t off = 0;
  auto alloc = [&](size_t bytes) {
    void* p = base + off;
    off += (bytes + 255) & ~(size_t)255;
    return p;
  };
  _Float16* w1t = (_Float16*)alloc((size_t)NEXP * FDIM * DDIM * 2);
  _Float16* w2t = (_Float16*)alloc((size_t)NEXP * DDIM * FDIM * 2);
  _Float16* Xg = (_Float16*)alloc((size_t)MAX_ROWS * DDIM * 2);
  int* row_map = (int*)alloc(MAX_ROWS * 4);
  float* row_w = (float*)alloc(MAX_ROWS * 4);
  int* tok_e = (int*)alloc(N_TOK * 2 * 4);
  float* tok_w = (float*)alloc(N_TOK * 2 * 4);
  int* meta = (int*)alloc(1024);
  size_t fixed = off;

  // F-chunking so the H buffer fits the provided workspace.
  int NC = 1;
  while (NC < 16 && fixed + (size_t)MAX_ROWS * (FDIM / NC) * 2 > ws_size) NC *= 2;
  int Fc = FDIM / NC;
  _Float16* H = (_Float16*)alloc((size_t)MAX_ROWS * Fc * 2);

  hipMemsetAsync(out, 0, (size_t)N_TOK * DDIM * 4, stream);
  hipMemsetAsync(meta, 0, 64, stream);                 // counts + fill
  hipMemsetAsync(row_map, 0xFF, MAX_ROWS * 4, stream); // -1 sentinels

  conv_transpose<<<dim3(FDIM / 32, DDIM / 32, NEXP), dim3(32, 8), 0, stream>>>(w1, w1t, DDIM, FDIM);
  conv_transpose<<<dim3(DDIM / 32, FDIM / 32, NEXP), dim3(32, 8), 0, stream>>>(w2, w2t, FDIM, DDIM);
  router_kernel<<<N_TOK / 4, 256, 0, stream>>>(x, rw, tok_e, tok_w, meta);
  offsets_kernel<<<1, 1, 0, stream>>>(meta);
  gather_kernel<<<N_TOK * 2 / 256, 256, 0, stream>>>(tok_e, tok_w, meta, row_map, row_w);
  xg_fill_kernel<<<MAX_ROWS, 128, 0, stream>>>(x, row_map, Xg);

  const int* be = meta + 32;
  for (int c = 0; c < NC; ++c) {
    gemm_bt<0><<<dim3(MAX_BLOCKS, Fc / 128), 256, 0, stream>>>(
        Xg, w1t + (size_t)c * Fc * DDIM, be, DDIM, DDIM, DDIM,
        (long long)FDIM * DDIM, H, Fc, nullptr, nullptr, nullptr);
    gemm_bt<1><<<dim3(MAX_BLOCKS, DDIM / 128), 256, 0, stream>>>(
        H, w2t + (size_t)c * Fc, be, Fc, FDIM, Fc,
        (long long)DDIM * FDIM, nullptr, 0, out, row_map, row_w);
  }
}

// Round 4
// 1039.299 us; speedup vs baseline: 1.0030x; 1.0014x over previous
//
#include <hip/hip_runtime.h>
#include <stdint.h>

#define N_TOK 8192
#define DDIM 1024
#define FDIM 4096
#define NEXP 8
#define MAX_BLOCKS 137
#define MAX_ROWS (MAX_BLOCKS * 128)

typedef _Float16 half8 __attribute__((ext_vector_type(8)));
typedef float floatx4 __attribute__((ext_vector_type(4)));

__device__ __forceinline__ void gload_lds16(const void* g, void* l) {
  __builtin_amdgcn_global_load_lds(
      (const __attribute__((address_space(1))) unsigned int*)(uintptr_t)g,
      (__attribute__((address_space(3))) unsigned int*)(uint32_t)(uintptr_t)l,
      16, 0, 0);
}

// ---------------- weight convert + transpose (fp32 [R][C] -> fp16 [C][R]) ----
__global__ void conv_transpose(const float* __restrict__ src,
                               _Float16* __restrict__ dst, int R, int C) {
  __shared__ float t[32][33];
  int e = blockIdx.z;
  const float* s = src + (size_t)e * R * C;
  _Float16* d = dst + (size_t)e * R * C;
  int c0 = blockIdx.x * 32, r0 = blockIdx.y * 32;
  int tx = threadIdx.x, ty = threadIdx.y;
#pragma unroll
  for (int i = 0; i < 32; i += 8)
    t[ty + i][tx] = s[(size_t)(r0 + ty + i) * C + c0 + tx];
  __syncthreads();
#pragma unroll
  for (int i = 0; i < 32; i += 8)
    d[(size_t)(c0 + ty + i) * R + r0 + tx] = (_Float16)t[tx][ty + i];
}

// ---------------- router: logits, top-2, softmax(fp32), counts --------------
__global__ __launch_bounds__(256) void router_kernel(
    const float* __restrict__ x, const float* __restrict__ rw,
    int* __restrict__ tok_e, float* __restrict__ tok_w, int* __restrict__ meta) {
  __shared__ float srw[NEXP * DDIM];
  int tid = threadIdx.x;
  const float4* rw4 = (const float4*)rw;
  float4* srw4 = (float4*)srw;
#pragma unroll
  for (int i = 0; i < 8; ++i) srw4[tid + i * 256] = rw4[tid + i * 256];
  __syncthreads();

  int wv = tid >> 6, l = tid & 63;
  int t = blockIdx.x * 4 + wv;
  const float4* xr = (const float4*)(x + (size_t)t * DDIM + l * 16);
  float4 xv[4];
#pragma unroll
  for (int i = 0; i < 4; ++i) xv[i] = xr[i];

  float logit[NEXP];
#pragma unroll
  for (int e = 0; e < NEXP; ++e) {
    const float4* wr4 = (const float4*)(srw + e * DDIM + l * 16);
    float acc = 0.f;
#pragma unroll
    for (int i = 0; i < 4; ++i) {
      float4 w4 = wr4[i];
      acc += xv[i].x * w4.x + xv[i].y * w4.y + xv[i].z * w4.z + xv[i].w * w4.w;
    }
#pragma unroll
    for (int off = 32; off > 0; off >>= 1) acc += __shfl_xor(acc, off);
    logit[e] = acc;
  }
  if (l == 0) {
    int i1 = 0;
    float v1 = logit[0];
#pragma unroll
    for (int e = 1; e < NEXP; ++e)
      if (logit[e] > v1) { v1 = logit[e]; i1 = e; }
    int i2 = -1;
    float v2 = -1e30f;
#pragma unroll
    for (int e = 0; e < NEXP; ++e)
      if (e != i1 && logit[e] > v2) { v2 = logit[e]; i2 = e; }
    float ex = expf(v2 - v1);  // v2 <= v1
    float denom = 1.f + ex;
    tok_e[2 * t] = i1;
    tok_e[2 * t + 1] = i2;
    tok_w[2 * t] = 1.f / denom;
    tok_w[2 * t + 1] = ex / denom;
    atomicAdd(&meta[i1], 1);
    atomicAdd(&meta[i2], 1);
  }
}

// ---------------- offsets: padded segments + block->expert table ------------
__global__ void offsets_kernel(int* meta) {
  int* counts = meta;
  int* fill = meta + 8;
  int* seg = meta + 16;   // [9]
  int* be = meta + 32;    // [MAX_BLOCKS]
  int s = 0;
  for (int e = 0; e < NEXP; ++e) {
    seg[e] = s;
    fill[e] = s;
    s += (counts[e] + 127) & ~127;
  }
  seg[NEXP] = s;
  for (int b = 0; b < MAX_BLOCKS; ++b) {
    int ee = -1;
    int row = b * 128;
    for (int e = 0; e < NEXP; ++e)
      if (row >= seg[e] && row < seg[e + 1]) ee = e;
    be[b] = ee;
  }
}

// ---------------- gather: pair -> slot ---------------------------------------
__global__ void gather_kernel(const int* __restrict__ tok_e,
                              const float* __restrict__ tok_w, int* meta,
                              int* __restrict__ row_map, float* __restrict__ row_w) {
  int p = blockIdx.x * 256 + threadIdx.x;  // 0..16383
  int e = tok_e[p];
  int pos = atomicAdd(&meta[8 + e], 1);
  row_map[pos] = p >> 1;
  row_w[pos] = tok_w[p];
}

// ---------------- Xg fill: gather x rows as fp16 (zeros for pads) -----------
__global__ void xg_fill_kernel(const float* __restrict__ x,
                               const int* __restrict__ row_map,
                               _Float16* __restrict__ Xg) {
  int r = blockIdx.x, t = threadIdx.x;
  int n = row_map[r];
  half8 h = {0, 0, 0, 0, 0, 0, 0, 0};
  if (n >= 0) {
    const float4* s = (const float4*)(x + (size_t)n * DDIM + t * 8);
    float4 a = s[0], b = s[1];
    h[0] = (_Float16)a.x; h[1] = (_Float16)a.y;
    h[2] = (_Float16)a.z; h[3] = (_Float16)a.w;
    h[4] = (_Float16)b.x; h[5] = (_Float16)b.y;
    h[6] = (_Float16)b.z; h[7] = (_Float16)b.w;
  }
  *(half8*)(Xg + (size_t)r * DDIM + t * 8) = h;
}

// ---------------- grouped GEMM (A[M,K] x B^T[N,K]), 128x128x64 --------------
// EPI=0: gelu -> Hout fp16.  EPI=1: atomicAdd(out[token], w * val).
template <int EPI>
__global__ __launch_bounds__(256) void gemm_bt(
    const _Float16* __restrict__ A, const _Float16* __restrict__ Bbase,
    const int* __restrict__ be, int lda, int ldb, int K, long long b_estride,
    _Float16* __restrict__ Hout, int ldh, float* __restrict__ out,
    const int* __restrict__ row_map, const float* __restrict__ row_w) {
  int e = be[blockIdx.x];
  if (e < 0) return;
  const _Float16* Ab = A + (size_t)blockIdx.x * 128 * lda;
  const _Float16* Bb = Bbase + (size_t)e * b_estride + (size_t)blockIdx.y * 128 * ldb;

  __shared__ __align__(16) _Float16 sA[128 * 64];
  __shared__ __align__(16) _Float16 sB[128 * 64];

  int tid = threadIdx.x;
  int w = tid >> 6, l = tid & 63;
  int wr = (w >> 1) * 64, wc = (w & 1) * 64;

  floatx4 acc[4][4] = {};

  int r0 = (l >> 3), kc = (l & 7) * 8;
  for (int kt = 0; kt < K; kt += 64) {
    const _Float16* As = Ab + kt;
    const _Float16* Bs = Bb + kt;
#pragma unroll
    for (int it = 0; it < 4; ++it) {
      int c = it * 4 + w;       // 16 chunks of 8 rows (1KB each)
      int row = c * 8 + r0;
      gload_lds16(As + (size_t)row * lda + kc, (void*)(sA + c * 512));
      gload_lds16(Bs + (size_t)row * ldb + kc, (void*)(sB + c * 512));
    }
    __syncthreads();  // drains vmcnt before reads

    half8 af[2][4], bf[2][4];
#pragma unroll
    for (int kk = 0; kk < 2; ++kk) {
#pragma unroll
      for (int m = 0; m < 4; ++m) {
        af[kk][m] = *(const half8*)&sA[(wr + m * 16 + (l & 15)) * 64 + kk * 32 + (l >> 4) * 8];
        bf[kk][m] = *(const half8*)&sB[(wc + m * 16 + (l & 15)) * 64 + kk * 32 + (l >> 4) * 8];
      }
    }
#pragma unroll
    for (int kk = 0; kk < 2; ++kk)
#pragma unroll
      for (int m = 0; m < 4; ++m)
#pragma unroll
        for (int n = 0; n < 4; ++n)
          acc[m][n] = __builtin_amdgcn_mfma_f32_16x16x32_f16(af[kk][m], bf[kk][n], acc[m][n], 0, 0, 0);
    __syncthreads();  // before next stage overwrites LDS
  }

  if (EPI == 0) {
#pragma unroll
    for (int m = 0; m < 4; ++m) {
#pragma unroll
      for (int j = 0; j < 4; ++j) {
        size_t r = (size_t)blockIdx.x * 128 + wr + m * 16 + (l >> 4) * 4 + j;
        _Float16* hp = Hout + r * ldh + (size_t)blockIdx.y * 128 + wc + (l & 15);
#pragma unroll
        for (int n = 0; n < 4; ++n) {
          float v = acc[m][n][j];
          v = 0.5f * v * (1.0f + erff(v * 0.70710678118f));  // exact gelu
          hp[n * 16] = (_Float16)v;
        }
      }
    }
  } else {
#pragma unroll
    for (int m = 0; m < 4; ++m) {
#pragma unroll
      for (int j = 0; j < 4; ++j) {
        int r = blockIdx.x * 128 + wr + m * 16 + (l >> 4) * 4 + j;
        int tok = row_map[r];
        if (tok < 0) continue;
        float wgt = row_w[r];
        float* op = out + (size_t)tok * DDIM + (size_t)blockIdx.y * 128 + wc + (l & 15);
#pragma unroll
        for (int n = 0; n < 4; ++n) atomicAdd(op + n * 16, wgt * acc[m][n][j]);
      }
    }
  }
}

// ---------------- launch -----------------------------------------------------
extern "C" void kernel_launch(void* const* d_in, const int* in_sizes, int n_in,
                              void* d_out, int out_size, void* d_ws, size_t ws_size,
                              hipStream_t stream) {
  const float* x = (const float*)d_in[0];
  const float* rw = (const float*)d_in[1];
  const float* w1 = (const float*)d_in[2];
  const float* w2 = (const float*)d_in[3];
  float* out = (float*)d_out;

  char* base = (char*)d_ws;
  size_t off = 0;
  auto alloc = [&](size_t bytes) {
    void* p = base + off;
    off += (bytes + 255) & ~(size_t)255;
    return p;
  };
  _Float16* w1t = (_Float16*)alloc((size_t)NEXP * FDIM * DDIM * 2);
  _Float16* w2t = (_Float16*)alloc((size_t)NEXP * DDIM * FDIM * 2);
  _Float16* Xg = (_Float16*)alloc((size_t)MAX_ROWS * DDIM * 2);
  int* row_map = (int*)alloc(MAX_ROWS * 4);
  float* row_w = (float*)alloc(MAX_ROWS * 4);
  int* tok_e = (int*)alloc(N_TOK * 2 * 4);
  float* tok_w = (float*)alloc(N_TOK * 2 * 4);
  int* meta = (int*)alloc(1024);
  size_t fixed = off;

  // F-chunking so the H buffer fits the provided workspace.
  int NC = 1;
  while (NC < 16 && fixed + (size_t)MAX_ROWS * (FDIM / NC) * 2 > ws_size) NC *= 2;
  int Fc = FDIM / NC;
  _Float16* H = (_Float16*)alloc((size_t)MAX_ROWS * Fc * 2);

  hipMemsetAsync(out, 0, (size_t)N_TOK * DDIM * 4, stream);
  hipMemsetAsync(meta, 0, 64, stream);                 // counts + fill
  hipMemsetAsync(row_map, 0xFF, MAX_ROWS * 4, stream); // -1 sentinels

  conv_transpose<<<dim3(FDIM / 32, DDIM / 32, NEXP), dim3(32, 8), 0, stream>>>(w1, w1t, DDIM, FDIM);
  conv_transpose<<<dim3(DDIM / 32, FDIM / 32, NEXP), dim3(32, 8), 0, stream>>>(w2, w2t, FDIM, DDIM);
  router_kernel<<<N_TOK / 4, 256, 0, stream>>>(x, rw, tok_e, tok_w, meta);
  offsets_kernel<<<1, 1, 0, stream>>>(meta);
  gather_kernel<<<N_TOK * 2 / 256, 256, 0, stream>>>(tok_e, tok_w, meta, row_map, row_w);
  xg_fill_kernel<<<MAX_ROWS, 128, 0, stream>>>(x, row_map, Xg);

  const int* be = meta + 32;
  for (int c = 0; c < NC; ++c) {
    gemm_bt<0><<<dim3(MAX_BLOCKS, Fc / 128), 256, 0, stream>>>(
        Xg, w1t + (size_t)c * Fc * DDIM, be, DDIM, DDIM, DDIM,
        (long long)FDIM * DDIM, H, Fc, nullptr, nullptr, nullptr);
    gemm_bt<1><<<dim3(MAX_BLOCKS, DDIM / 128), 256, 0, stream>>>(
        H, w2t + (size_t)c * Fc, be, Fc, FDIM, Fc,
        (long long)DDIM * FDIM, nullptr, 0, out, row_map, row_w);
  }
}

// Round 5
// 1007.047 us; speedup vs baseline: 1.0351x; 1.0320x over previous
//
#include <hip/hip_runtime.h>
#include <stdint.h>

#define N_TOK 8192
#define DDIM 1024
#define FDIM 4096
#define NEXP 8
#define MAX_BLOCKS 137
#define MAX_ROWS (MAX_BLOCKS * 128)

typedef _Float16 half8 __attribute__((ext_vector_type(8)));
typedef float floatx4 __attribute__((ext_vector_type(4)));

__device__ __forceinline__ void gload_lds16(const void* g, void* l) {
  __builtin_amdgcn_global_load_lds(
      (const __attribute__((address_space(1))) unsigned int*)(uintptr_t)g,
      (__attribute__((address_space(3))) unsigned int*)(uint32_t)(uintptr_t)l,
      16, 0, 0);
}

// ---- convert+transpose: fp32 src[R][C] -> fp16 dst[C][R], 64x64 tiles ------
__global__ __launch_bounds__(256) void conv_transpose(
    const float* __restrict__ src, _Float16* __restrict__ dst, int R, int C) {
  __shared__ float t[64][65];
  int e = blockIdx.z;
  const float* s = src + (size_t)e * R * C;
  _Float16* d = dst + (size_t)e * R * C;
  int c0 = blockIdx.x * 64, r0 = blockIdx.y * 64;
  int tid = threadIdx.x;
  int rl = tid >> 4, c4 = (tid & 15) * 4;
#pragma unroll
  for (int i = 0; i < 4; ++i) {
    float4 v = *(const float4*)(s + (size_t)(r0 + rl + i * 16) * C + c0 + c4);
    *(float4*)&t[rl + i * 16][c4] = v;
  }
  __syncthreads();
  int dr = tid >> 2, cc0 = (tid & 3) * 16;  // dst row = src col
#pragma unroll
  for (int h = 0; h < 2; ++h) {
    half8 o;
#pragma unroll
    for (int k = 0; k < 8; ++k) o[k] = (_Float16)t[cc0 + h * 8 + k][dr];
    *(half8*)(d + (size_t)(c0 + dr) * R + r0 + cc0 + h * 8) = o;
  }
}

// ---------------- router: logits, top-2, softmax(fp32), counts --------------
__global__ __launch_bounds__(256) void router_kernel(
    const float* __restrict__ x, const float* __restrict__ rw,
    int* __restrict__ tok_e, float* __restrict__ tok_w, int* __restrict__ meta) {
  __shared__ float srw[NEXP * DDIM];
  int tid = threadIdx.x;
  const float4* rw4 = (const float4*)rw;
  float4* srw4 = (float4*)srw;
#pragma unroll
  for (int i = 0; i < 8; ++i) srw4[tid + i * 256] = rw4[tid + i * 256];
  __syncthreads();

  int wv = tid >> 6, l = tid & 63;
  int t = blockIdx.x * 4 + wv;
  const float4* xr = (const float4*)(x + (size_t)t * DDIM + l * 16);
  float4 xv[4];
#pragma unroll
  for (int i = 0; i < 4; ++i) xv[i] = xr[i];

  float logit[NEXP];
#pragma unroll
  for (int e = 0; e < NEXP; ++e) {
    const float4* wr4 = (const float4*)(srw + e * DDIM + l * 16);
    float acc = 0.f;
#pragma unroll
    for (int i = 0; i < 4; ++i) {
      float4 w4 = wr4[i];
      acc += xv[i].x * w4.x + xv[i].y * w4.y + xv[i].z * w4.z + xv[i].w * w4.w;
    }
#pragma unroll
    for (int off = 32; off > 0; off >>= 1) acc += __shfl_xor(acc, off);
    logit[e] = acc;
  }
  if (l == 0) {
    int i1 = 0;
    float v1 = logit[0];
#pragma unroll
    for (int e = 1; e < NEXP; ++e)
      if (logit[e] > v1) { v1 = logit[e]; i1 = e; }
    int i2 = -1;
    float v2 = -1e30f;
#pragma unroll
    for (int e = 0; e < NEXP; ++e)
      if (e != i1 && logit[e] > v2) { v2 = logit[e]; i2 = e; }
    float ex = expf(v2 - v1);  // v2 <= v1
    float denom = 1.f + ex;
    tok_e[2 * t] = i1;
    tok_e[2 * t + 1] = i2;
    tok_w[2 * t] = 1.f / denom;
    tok_w[2 * t + 1] = ex / denom;
    atomicAdd(&meta[i1], 1);
    atomicAdd(&meta[i2], 1);
  }
}

// ---- offsets: padded segments + block->expert table (parallel, 64 thr) -----
__global__ void offsets_kernel(int* meta) {
  __shared__ int seg[NEXP + 1];
  int l = threadIdx.x;
  if (l == 0) {
    int s = 0;
    for (int e = 0; e < NEXP; ++e) {
      seg[e] = s;
      meta[16 + e] = s;
      meta[8 + e] = s;  // fill cursor starts at segment base
      s += (meta[e] + 127) & ~127;
    }
    seg[NEXP] = s;
    meta[16 + NEXP] = s;
  }
  __syncthreads();
  for (int b = l; b < MAX_BLOCKS; b += 64) {
    int row = b * 128, ee = -1;
#pragma unroll
    for (int e = 0; e < NEXP; ++e)
      if (row >= seg[e] && row < seg[e + 1]) ee = e;
    meta[32 + b] = ee;
  }
}

// ---- gather: pair -> slot; also inverse map pair -> position ---------------
__global__ void gather_kernel(const int* __restrict__ tok_e, int* meta,
                              int* __restrict__ row_map, int* __restrict__ inv_pos) {
  int p = blockIdx.x * 256 + threadIdx.x;  // 0..16383
  int e = tok_e[p];
  int pos = atomicAdd(&meta[8 + e], 1);
  row_map[pos] = p >> 1;
  inv_pos[p] = pos;
}

// ---- Xg fill: gather x rows as fp16 (zeros for pads) -----------------------
__global__ void xg_fill_kernel(const float* __restrict__ x,
                               const int* __restrict__ row_map,
                               _Float16* __restrict__ Xg) {
  int r = blockIdx.x, t = threadIdx.x;
  int n = row_map[r];
  half8 h = {0, 0, 0, 0, 0, 0, 0, 0};
  if (n >= 0) {
    const float4* s = (const float4*)(x + (size_t)n * DDIM + t * 8);
    float4 a = s[0], b = s[1];
    h[0] = (_Float16)a.x; h[1] = (_Float16)a.y;
    h[2] = (_Float16)a.z; h[3] = (_Float16)a.w;
    h[4] = (_Float16)b.x; h[5] = (_Float16)b.y;
    h[6] = (_Float16)b.z; h[7] = (_Float16)b.w;
  }
  *(half8*)(Xg + (size_t)r * DDIM + t * 8) = h;
}

// ---- grouped GEMM (A[M,K] x B^T[N,K]), 128x128x64 --------------------------
// EPI=0: gelu -> Hout fp16.  EPI=1: fp32 store (or +=) into Y[row][DDIM].
template <int EPI>
__global__ __launch_bounds__(256) void gemm_bt(
    const _Float16* __restrict__ A, const _Float16* __restrict__ Bbase,
    const int* __restrict__ be, int lda, int ldb, int K, long long b_estride,
    _Float16* __restrict__ Hout, int ldh, float* __restrict__ Yout, int accum) {
  int e = be[blockIdx.x];
  if (e < 0) return;
  const _Float16* Ab = A + (size_t)blockIdx.x * 128 * lda;
  const _Float16* Bb = Bbase + (size_t)e * b_estride + (size_t)blockIdx.y * 128 * ldb;

  __shared__ __align__(16) _Float16 sA[128 * 64];
  __shared__ __align__(16) _Float16 sB[128 * 64];

  int tid = threadIdx.x;
  int w = tid >> 6, l = tid & 63;
  int wr = (w >> 1) * 64, wc = (w & 1) * 64;

  floatx4 acc[4][4] = {};

  int r0 = (l >> 3), kc = (l & 7) * 8;
  for (int kt = 0; kt < K; kt += 64) {
    const _Float16* As = Ab + kt;
    const _Float16* Bs = Bb + kt;
#pragma unroll
    for (int it = 0; it < 4; ++it) {
      int c = it * 4 + w;  // 16 chunks of 8 rows (1KB each)
      int row = c * 8 + r0;
      gload_lds16(As + (size_t)row * lda + kc, (void*)(sA + c * 512));
      gload_lds16(Bs + (size_t)row * ldb + kc, (void*)(sB + c * 512));
    }
    __syncthreads();  // drains vmcnt before reads

    half8 af[2][4], bf[2][4];
#pragma unroll
    for (int kk = 0; kk < 2; ++kk) {
#pragma unroll
      for (int m = 0; m < 4; ++m) {
        af[kk][m] = *(const half8*)&sA[(wr + m * 16 + (l & 15)) * 64 + kk * 32 + (l >> 4) * 8];
        bf[kk][m] = *(const half8*)&sB[(wc + m * 16 + (l & 15)) * 64 + kk * 32 + (l >> 4) * 8];
      }
    }
#pragma unroll
    for (int kk = 0; kk < 2; ++kk)
#pragma unroll
      for (int m = 0; m < 4; ++m)
#pragma unroll
        for (int n = 0; n < 4; ++n)
          acc[m][n] = __builtin_amdgcn_mfma_f32_16x16x32_f16(af[kk][m], bf[kk][n], acc[m][n], 0, 0, 0);
    __syncthreads();  // before next stage overwrites LDS
  }

  if (EPI == 0) {
#pragma unroll
    for (int m = 0; m < 4; ++m) {
#pragma unroll
      for (int j = 0; j < 4; ++j) {
        size_t r = (size_t)blockIdx.x * 128 + wr + m * 16 + (l >> 4) * 4 + j;
        _Float16* hp = Hout + r * ldh + (size_t)blockIdx.y * 128 + wc + (l & 15);
#pragma unroll
        for (int n = 0; n < 4; ++n) {
          float v = acc[m][n][j];
          v = 0.5f * v * (1.0f + erff(v * 0.70710678118f));  // exact gelu
          hp[n * 16] = (_Float16)v;
        }
      }
    }
  } else {
#pragma unroll
    for (int m = 0; m < 4; ++m) {
#pragma unroll
      for (int j = 0; j < 4; ++j) {
        size_t r = (size_t)blockIdx.x * 128 + wr + m * 16 + (l >> 4) * 4 + j;
        float* yp = Yout + r * DDIM + (size_t)blockIdx.y * 128 + wc + (l & 15);
        if (accum) {
#pragma unroll
          for (int n = 0; n < 4; ++n) yp[n * 16] += acc[m][n][j];
        } else {
#pragma unroll
          for (int n = 0; n < 4; ++n) yp[n * 16] = acc[m][n][j];
        }
      }
    }
  }
}

// ---- combine: out[t] = w0 * Y[pos0] + w1 * Y[pos1] -------------------------
__global__ __launch_bounds__(128) void combine_kernel(
    const float* __restrict__ Y, const int* __restrict__ inv_pos,
    const float* __restrict__ tok_w, float* __restrict__ out) {
  int t = blockIdx.x, l = threadIdx.x;
  int p0 = inv_pos[2 * t], p1 = inv_pos[2 * t + 1];
  float w0 = tok_w[2 * t], w1 = tok_w[2 * t + 1];
  const float4* y0 = (const float4*)(Y + (size_t)p0 * DDIM) + l * 2;
  const float4* y1 = (const float4*)(Y + (size_t)p1 * DDIM) + l * 2;
  float4* o = (float4*)(out + (size_t)t * DDIM) + l * 2;
#pragma unroll
  for (int i = 0; i < 2; ++i) {
    float4 a = y0[i], b = y1[i];
    float4 r;
    r.x = w0 * a.x + w1 * b.x;
    r.y = w0 * a.y + w1 * b.y;
    r.z = w0 * a.z + w1 * b.z;
    r.w = w0 * a.w + w1 * b.w;
    o[i] = r;
  }
}

// ---------------- launch -----------------------------------------------------
extern "C" void kernel_launch(void* const* d_in, const int* in_sizes, int n_in,
                              void* d_out, int out_size, void* d_ws, size_t ws_size,
                              hipStream_t stream) {
  const float* x = (const float*)d_in[0];
  const float* rw = (const float*)d_in[1];
  const float* w1 = (const float*)d_in[2];
  const float* w2 = (const float*)d_in[3];
  float* out = (float*)d_out;

  char* base = (char*)d_ws;
  size_t off = 0;
  auto alloc = [&](size_t bytes) {
    void* p = base + off;
    off += (bytes + 255) & ~(size_t)255;
    return p;
  };
  _Float16* w1t = (_Float16*)alloc((size_t)NEXP * FDIM * DDIM * 2);
  _Float16* w2t = (_Float16*)alloc((size_t)NEXP * DDIM * FDIM * 2);
  _Float16* Xg = (_Float16*)alloc((size_t)MAX_ROWS * DDIM * 2);
  float* Y = (float*)alloc((size_t)MAX_ROWS * DDIM * 4);
  int* row_map = (int*)alloc(MAX_ROWS * 4);
  int* inv_pos = (int*)alloc(N_TOK * 2 * 4);
  int* tok_e = (int*)alloc(N_TOK * 2 * 4);
  float* tok_w = (float*)alloc(N_TOK * 2 * 4);
  int* meta = (int*)alloc(1024);
  size_t fixed = off;

  // F-chunking so the H buffer fits the provided workspace.
  int NC = 1;
  while (NC < 16 && fixed + (size_t)MAX_ROWS * (FDIM / NC) * 2 > ws_size) NC *= 2;
  int Fc = FDIM / NC;
  _Float16* H = (_Float16*)alloc((size_t)MAX_ROWS * Fc * 2);

  hipMemsetAsync(meta, 0, 64, stream);                  // counts + fill
  hipMemsetAsync(row_map, 0xFF, MAX_ROWS * 4, stream);  // -1 sentinels

  conv_transpose<<<dim3(FDIM / 64, DDIM / 64, NEXP), 256, 0, stream>>>(w1, w1t, DDIM, FDIM);
  conv_transpose<<<dim3(DDIM / 64, FDIM / 64, NEXP), 256, 0, stream>>>(w2, w2t, FDIM, DDIM);
  router_kernel<<<N_TOK / 4, 256, 0, stream>>>(x, rw, tok_e, tok_w, meta);
  offsets_kernel<<<1, 64, 0, stream>>>(meta);
  gather_kernel<<<N_TOK * 2 / 256, 256, 0, stream>>>(tok_e, meta, row_map, inv_pos);
  xg_fill_kernel<<<MAX_ROWS, 128, 0, stream>>>(x, row_map, Xg);

  const int* be = meta + 32;
  for (int c = 0; c < NC; ++c) {
    gemm_bt<0><<<dim3(MAX_BLOCKS, Fc / 128), 256, 0, stream>>>(
        Xg, w1t + (size_t)c * Fc * DDIM, be, DDIM, DDIM, DDIM,
        (long long)FDIM * DDIM, H, Fc, nullptr, 0);
    gemm_bt<1><<<dim3(MAX_BLOCKS, DDIM / 128), 256, 0, stream>>>(
        H, w2t + (size_t)c * Fc, be, Fc, FDIM, Fc,
        (long long)DDIM * FDIM, nullptr, 0, Y, c > 0);
  }
  combine_kernel<<<N_TOK, 128, 0, stream>>>(Y, inv_pos, tok_w, out);
}

// Round 6
// 957.543 us; speedup vs baseline: 1.0886x; 1.0517x over previous
//
#include <hip/hip_runtime.h>
#include <stdint.h>

#define N_TOK 8192
#define DDIM 1024
#define FDIM 4096
#define NEXP 8
#define MAX_BLOCKS 137
#define MAX_ROWS (MAX_BLOCKS * 128)

typedef _Float16 half8 __attribute__((ext_vector_type(8)));
typedef float floatx4 __attribute__((ext_vector_type(4)));

__device__ __forceinline__ void gload_lds16(const void* g, void* l) {
  __builtin_amdgcn_global_load_lds(
      (const __attribute__((address_space(1))) unsigned int*)(uintptr_t)g,
      (__attribute__((address_space(3))) unsigned int*)(uint32_t)(uintptr_t)l,
      16, 0, 0);
}

// fast exact-enough gelu: tanh form, max |dev| vs erf-gelu ~1e-3
__device__ __forceinline__ float gelu_fast(float v) {
  float u = v * (0.7978845608f + 0.0356774081f * v * v);
  float ev = __expf(2.f * u);
  float th = 1.f - 2.f / (ev + 1.f);  // tanh(u), safe at +/-inf
  return 0.5f * v * (1.f + th);
}

// ---- convert+transpose: fp32 src[R][C] -> fp16 dst[C][R], 64x64 tiles ------
__global__ __launch_bounds__(256) void conv_transpose(
    const float* __restrict__ src, _Float16* __restrict__ dst, int R, int C) {
  __shared__ float t[64][65];
  int e = blockIdx.z;
  const float* s = src + (size_t)e * R * C;
  _Float16* d = dst + (size_t)e * R * C;
  int c0 = blockIdx.x * 64, r0 = blockIdx.y * 64;
  int tid = threadIdx.x;
  int rl = tid >> 4, c4 = (tid & 15) * 4;
#pragma unroll
  for (int i = 0; i < 4; ++i) {
    float4 v = *(const float4*)(s + (size_t)(r0 + rl + i * 16) * C + c0 + c4);
    *(float4*)&t[rl + i * 16][c4] = v;
  }
  __syncthreads();
  int dr = tid >> 2, cc0 = (tid & 3) * 16;  // dst row = src col
#pragma unroll
  for (int h = 0; h < 2; ++h) {
    half8 o;
#pragma unroll
    for (int k = 0; k < 8; ++k) o[k] = (_Float16)t[cc0 + h * 8 + k][dr];
    *(half8*)(d + (size_t)(c0 + dr) * R + r0 + cc0 + h * 8) = o;
  }
}

// ---------------- router: logits, top-2, softmax(fp32), counts --------------
__global__ __launch_bounds__(256) void router_kernel(
    const float* __restrict__ x, const float* __restrict__ rw,
    int* __restrict__ tok_e, float* __restrict__ tok_w, int* __restrict__ meta) {
  __shared__ float srw[NEXP * DDIM];
  int tid = threadIdx.x;
  const float4* rw4 = (const float4*)rw;
  float4* srw4 = (float4*)srw;
#pragma unroll
  for (int i = 0; i < 8; ++i) srw4[tid + i * 256] = rw4[tid + i * 256];
  __syncthreads();

  int wv = tid >> 6, l = tid & 63;
  int t = blockIdx.x * 4 + wv;
  const float4* xr = (const float4*)(x + (size_t)t * DDIM + l * 16);
  float4 xv[4];
#pragma unroll
  for (int i = 0; i < 4; ++i) xv[i] = xr[i];

  float logit[NEXP];
#pragma unroll
  for (int e = 0; e < NEXP; ++e) {
    const float4* wr4 = (const float4*)(srw + e * DDIM + l * 16);
    float acc = 0.f;
#pragma unroll
    for (int i = 0; i < 4; ++i) {
      float4 w4 = wr4[i];
      acc += xv[i].x * w4.x + xv[i].y * w4.y + xv[i].z * w4.z + xv[i].w * w4.w;
    }
#pragma unroll
    for (int off = 32; off > 0; off >>= 1) acc += __shfl_xor(acc, off);
    logit[e] = acc;
  }
  if (l == 0) {
    int i1 = 0;
    float v1 = logit[0];
#pragma unroll
    for (int e = 1; e < NEXP; ++e)
      if (logit[e] > v1) { v1 = logit[e]; i1 = e; }
    int i2 = -1;
    float v2 = -1e30f;
#pragma unroll
    for (int e = 0; e < NEXP; ++e)
      if (e != i1 && logit[e] > v2) { v2 = logit[e]; i2 = e; }
    float ex = expf(v2 - v1);  // v2 <= v1
    float denom = 1.f + ex;
    tok_e[2 * t] = i1;
    tok_e[2 * t + 1] = i2;
    tok_w[2 * t] = 1.f / denom;
    tok_w[2 * t + 1] = ex / denom;
    atomicAdd(&meta[i1], 1);
    atomicAdd(&meta[i2], 1);
  }
}

// ---- offsets: padded segments + block->expert table (parallel, 64 thr) -----
__global__ void offsets_kernel(int* meta) {
  __shared__ int seg[NEXP + 1];
  int l = threadIdx.x;
  if (l == 0) {
    int s = 0;
    for (int e = 0; e < NEXP; ++e) {
      seg[e] = s;
      meta[16 + e] = s;
      meta[8 + e] = s;  // fill cursor starts at segment base
      s += (meta[e] + 127) & ~127;
    }
    seg[NEXP] = s;
    meta[16 + NEXP] = s;
  }
  __syncthreads();
  for (int b = l; b < MAX_BLOCKS; b += 64) {
    int row = b * 128, ee = -1;
#pragma unroll
    for (int e = 0; e < NEXP; ++e)
      if (row >= seg[e] && row < seg[e + 1]) ee = e;
    meta[32 + b] = ee;
  }
}

// ---- gather: pair -> slot; also inverse map pair -> position ---------------
__global__ void gather_kernel(const int* __restrict__ tok_e, int* meta,
                              int* __restrict__ row_map, int* __restrict__ inv_pos) {
  int p = blockIdx.x * 256 + threadIdx.x;  // 0..16383
  int e = tok_e[p];
  int pos = atomicAdd(&meta[8 + e], 1);
  row_map[pos] = p >> 1;
  inv_pos[p] = pos;
}

// ---- Xg fill: gather x rows as fp16 (zeros for pads) -----------------------
__global__ void xg_fill_kernel(const float* __restrict__ x,
                               const int* __restrict__ row_map,
                               _Float16* __restrict__ Xg) {
  int r = blockIdx.x, t = threadIdx.x;
  int n = row_map[r];
  half8 h = {0, 0, 0, 0, 0, 0, 0, 0};
  if (n >= 0) {
    const float4* s = (const float4*)(x + (size_t)n * DDIM + t * 8);
    float4 a = s[0], b = s[1];
    h[0] = (_Float16)a.x; h[1] = (_Float16)a.y;
    h[2] = (_Float16)a.z; h[3] = (_Float16)a.w;
    h[4] = (_Float16)b.x; h[5] = (_Float16)b.y;
    h[6] = (_Float16)b.z; h[7] = (_Float16)b.w;
  }
  *(half8*)(Xg + (size_t)r * DDIM + t * 8) = h;
}

// ---- grouped GEMM (A[M,K] x B^T[N,K]), 128x128x64, 1D grid -----------------
// Block mapping: bijective XCD-chunked swizzle (m204), then y-fastest within
// the XCD chunk so each x-block's A panel stays L2-resident across its y-sweep.
// EPI=0: gelu -> Hout fp16.  EPI=1: fp32 store (or +=) into Y[row][DDIM].
template <int EPI>
__global__ __launch_bounds__(256) void gemm_bt(
    const _Float16* __restrict__ A, const _Float16* __restrict__ Bbase,
    const int* __restrict__ be, int lda, int ldb, int K, long long b_estride,
    _Float16* __restrict__ Hout, int ldh, float* __restrict__ Yout, int accum,
    int lyt) {
  // ---- block swizzle ----
  int o = blockIdx.x, nb = gridDim.x;
  int q = nb >> 3, r8 = nb & 7, xc = o & 7, oo = o >> 3;
  int wg = (xc < r8 ? xc * (q + 1) : r8 * (q + 1) + (xc - r8) * q) + oo;
  int by = wg & ((1 << lyt) - 1);
  int bx = wg >> lyt;

  int e = be[bx];
  if (e < 0) return;
  const _Float16* Ab = A + (size_t)bx * 128 * lda;
  const _Float16* Bb = Bbase + (size_t)e * b_estride + (size_t)by * 128 * ldb;

  __shared__ __align__(16) _Float16 sA[128 * 64];
  __shared__ __align__(16) _Float16 sB[128 * 64];

  int tid = threadIdx.x;
  int w = tid >> 6, l = tid & 63;
  int wr = (w >> 1) * 64, wc = (w & 1) * 64;

  floatx4 acc[4][4] = {};

  int r0 = (l >> 3), kc = (l & 7) * 8;
  for (int kt = 0; kt < K; kt += 64) {
    const _Float16* As = Ab + kt;
    const _Float16* Bs = Bb + kt;
#pragma unroll
    for (int it = 0; it < 4; ++it) {
      int c = it * 4 + w;  // 16 chunks of 8 rows (1KB each)
      int row = c * 8 + r0;
      gload_lds16(As + (size_t)row * lda + kc, (void*)(sA + c * 512));
      gload_lds16(Bs + (size_t)row * ldb + kc, (void*)(sB + c * 512));
    }
    __syncthreads();  // drains vmcnt before reads

    half8 af[2][4], bf[2][4];
#pragma unroll
    for (int kk = 0; kk < 2; ++kk) {
#pragma unroll
      for (int m = 0; m < 4; ++m) {
        af[kk][m] = *(const half8*)&sA[(wr + m * 16 + (l & 15)) * 64 + kk * 32 + (l >> 4) * 8];
        bf[kk][m] = *(const half8*)&sB[(wc + m * 16 + (l & 15)) * 64 + kk * 32 + (l >> 4) * 8];
      }
    }
#pragma unroll
    for (int kk = 0; kk < 2; ++kk)
#pragma unroll
      for (int m = 0; m < 4; ++m)
#pragma unroll
        for (int n = 0; n < 4; ++n)
          acc[m][n] = __builtin_amdgcn_mfma_f32_16x16x32_f16(af[kk][m], bf[kk][n], acc[m][n], 0, 0, 0);
    __syncthreads();  // before next stage overwrites LDS
  }

  if (EPI == 0) {
#pragma unroll
    for (int m = 0; m < 4; ++m) {
#pragma unroll
      for (int j = 0; j < 4; ++j) {
        size_t r = (size_t)bx * 128 + wr + m * 16 + (l >> 4) * 4 + j;
        _Float16* hp = Hout + r * ldh + (size_t)by * 128 + wc + (l & 15);
#pragma unroll
        for (int n = 0; n < 4; ++n) {
          hp[n * 16] = (_Float16)gelu_fast(acc[m][n][j]);
        }
      }
    }
  } else {
#pragma unroll
    for (int m = 0; m < 4; ++m) {
#pragma unroll
      for (int j = 0; j < 4; ++j) {
        size_t r = (size_t)bx * 128 + wr + m * 16 + (l >> 4) * 4 + j;
        float* yp = Yout + r * DDIM + (size_t)by * 128 + wc + (l & 15);
        if (accum) {
#pragma unroll
          for (int n = 0; n < 4; ++n) yp[n * 16] += acc[m][n][j];
        } else {
#pragma unroll
          for (int n = 0; n < 4; ++n) yp[n * 16] = acc[m][n][j];
        }
      }
    }
  }
}

// ---- combine: out[t] = w0 * Y[pos0] + w1 * Y[pos1] -------------------------
__global__ __launch_bounds__(128) void combine_kernel(
    const float* __restrict__ Y, const int* __restrict__ inv_pos,
    const float* __restrict__ tok_w, float* __restrict__ out) {
  int t = blockIdx.x, l = threadIdx.x;
  int p0 = inv_pos[2 * t], p1 = inv_pos[2 * t + 1];
  float w0 = tok_w[2 * t], w1 = tok_w[2 * t + 1];
  const float4* y0 = (const float4*)(Y + (size_t)p0 * DDIM) + l * 2;
  const float4* y1 = (const float4*)(Y + (size_t)p1 * DDIM) + l * 2;
  float4* o = (float4*)(out + (size_t)t * DDIM) + l * 2;
#pragma unroll
  for (int i = 0; i < 2; ++i) {
    float4 a = y0[i], b = y1[i];
    float4 r;
    r.x = w0 * a.x + w1 * b.x;
    r.y = w0 * a.y + w1 * b.y;
    r.z = w0 * a.z + w1 * b.z;
    r.w = w0 * a.w + w1 * b.w;
    o[i] = r;
  }
}

// ---------------- launch -----------------------------------------------------
extern "C" void kernel_launch(void* const* d_in, const int* in_sizes, int n_in,
                              void* d_out, int out_size, void* d_ws, size_t ws_size,
                              hipStream_t stream) {
  const float* x = (const float*)d_in[0];
  const float* rw = (const float*)d_in[1];
  const float* w1 = (const float*)d_in[2];
  const float* w2 = (const float*)d_in[3];
  float* out = (float*)d_out;

  char* base = (char*)d_ws;
  size_t off = 0;
  auto alloc = [&](size_t bytes) {
    void* p = base + off;
    off += (bytes + 255) & ~(size_t)255;
    return p;
  };
  _Float16* w1t = (_Float16*)alloc((size_t)NEXP * FDIM * DDIM * 2);
  _Float16* w2t = (_Float16*)alloc((size_t)NEXP * DDIM * FDIM * 2);
  _Float16* Xg = (_Float16*)alloc((size_t)MAX_ROWS * DDIM * 2);
  float* Y = (float*)alloc((size_t)MAX_ROWS * DDIM * 4);
  int* row_map = (int*)alloc(MAX_ROWS * 4);
  int* inv_pos = (int*)alloc(N_TOK * 2 * 4);
  int* tok_e = (int*)alloc(N_TOK * 2 * 4);
  float* tok_w = (float*)alloc(N_TOK * 2 * 4);
  int* meta = (int*)alloc(1024);
  size_t fixed = off;

  // F-chunking so the H buffer fits the provided workspace.
  int NC = 1;
  while (NC < 16 && fixed + (size_t)MAX_ROWS * (FDIM / NC) * 2 > ws_size) NC *= 2;
  int Fc = FDIM / NC;
  _Float16* H = (_Float16*)alloc((size_t)MAX_ROWS * Fc * 2);

  hipMemsetAsync(meta, 0, 64, stream);                  // counts + fill
  hipMemsetAsync(row_map, 0xFF, MAX_ROWS * 4, stream);  // -1 sentinels

  conv_transpose<<<dim3(FDIM / 64, DDIM / 64, NEXP), 256, 0, stream>>>(w1, w1t, DDIM, FDIM);
  conv_transpose<<<dim3(DDIM / 64, FDIM / 64, NEXP), 256, 0, stream>>>(w2, w2t, FDIM, DDIM);
  router_kernel<<<N_TOK / 4, 256, 0, stream>>>(x, rw, tok_e, tok_w, meta);
  offsets_kernel<<<1, 64, 0, stream>>>(meta);
  gather_kernel<<<N_TOK * 2 / 256, 256, 0, stream>>>(tok_e, meta, row_map, inv_pos);
  xg_fill_kernel<<<MAX_ROWS, 128, 0, stream>>>(x, row_map, Xg);

  const int* be = meta + 32;
  int yt1 = Fc / 128;
  int ly1 = 31 - __builtin_clz(yt1);  // Fc/128 is a power of two
  for (int c = 0; c < NC; ++c) {
    gemm_bt<0><<<dim3(MAX_BLOCKS * yt1), 256, 0, stream>>>(
        Xg, w1t + (size_t)c * Fc * DDIM, be, DDIM, DDIM, DDIM,
        (long long)FDIM * DDIM, H, Fc, nullptr, 0, ly1);
    gemm_bt<1><<<dim3(MAX_BLOCKS * 8), 256, 0, stream>>>(
        H, w2t + (size_t)c * Fc, be, Fc, FDIM, Fc,
        (long long)DDIM * FDIM, nullptr, 0, Y, c > 0, 3);
  }
  combine_kernel<<<N_TOK, 128, 0, stream>>>(Y, inv_pos, tok_w, out);
}

// Round 7
// 785.621 us; speedup vs baseline: 1.3268x; 1.2188x over previous
//
#include <hip/hip_runtime.h>
#include <stdint.h>

#define N_TOK 8192
#define DDIM 1024
#define FDIM 4096
#define NEXP 8
#define MAXB1 72                 // 256-row blocks: 16384 + 8*255 padded -> 72
#define MAX_ROWS (MAXB1 * 256)   // 18432

typedef _Float16 half8 __attribute__((ext_vector_type(8)));
typedef float floatx4 __attribute__((ext_vector_type(4)));

#define VMCNT(n) asm volatile("s_waitcnt vmcnt(" #n ")" ::: "memory")
#define LGKM0 asm volatile("s_waitcnt lgkmcnt(0)" ::: "memory")

__device__ __forceinline__ void gload_lds16(const void* g, void* l) {
  __builtin_amdgcn_global_load_lds(
      (const __attribute__((address_space(1))) unsigned int*)(uintptr_t)g,
      (__attribute__((address_space(3))) unsigned int*)(uint32_t)(uintptr_t)l,
      16, 0, 0);
}

// fast exact-enough gelu: tanh form, max |dev| vs erf-gelu ~1e-3
__device__ __forceinline__ float gelu_fast(float v) {
  float u = v * (0.7978845608f + 0.0356774081f * v * v);
  float ev = __expf(2.f * u);
  float th = 1.f - 2.f / (ev + 1.f);  // tanh(u), safe at +/-inf
  return 0.5f * v * (1.f + th);
}

// ---- convert+transpose: fp32 src[R][C] -> fp16 dst[C][R], 64x64 tiles ------
__global__ __launch_bounds__(256) void conv_transpose(
    const float* __restrict__ src, _Float16* __restrict__ dst, int R, int C) {
  __shared__ float t[64][65];
  int e = blockIdx.z;
  const float* s = src + (size_t)e * R * C;
  _Float16* d = dst + (size_t)e * R * C;
  int c0 = blockIdx.x * 64, r0 = blockIdx.y * 64;
  int tid = threadIdx.x;
  int rl = tid >> 4, c4 = (tid & 15) * 4;
#pragma unroll
  for (int i = 0; i < 4; ++i) {
    float4 v = *(const float4*)(s + (size_t)(r0 + rl + i * 16) * C + c0 + c4);
    *(float4*)&t[rl + i * 16][c4] = v;
  }
  __syncthreads();
  int dr = tid >> 2, cc0 = (tid & 3) * 16;  // dst row = src col
#pragma unroll
  for (int h = 0; h < 2; ++h) {
    half8 o;
#pragma unroll
    for (int k = 0; k < 8; ++k) o[k] = (_Float16)t[cc0 + h * 8 + k][dr];
    *(half8*)(d + (size_t)(c0 + dr) * R + r0 + cc0 + h * 8) = o;
  }
}

// ---------------- router: logits, top-2, softmax(fp32), counts --------------
__global__ __launch_bounds__(256) void router_kernel(
    const float* __restrict__ x, const float* __restrict__ rw,
    int* __restrict__ tok_e, float* __restrict__ tok_w, int* __restrict__ meta) {
  __shared__ float srw[NEXP * DDIM];
  int tid = threadIdx.x;
  const float4* rw4 = (const float4*)rw;
  float4* srw4 = (float4*)srw;
#pragma unroll
  for (int i = 0; i < 8; ++i) srw4[tid + i * 256] = rw4[tid + i * 256];
  __syncthreads();

  int wv = tid >> 6, l = tid & 63;
  int t = blockIdx.x * 4 + wv;
  const float4* xr = (const float4*)(x + (size_t)t * DDIM + l * 16);
  float4 xv[4];
#pragma unroll
  for (int i = 0; i < 4; ++i) xv[i] = xr[i];

  float logit[NEXP];
#pragma unroll
  for (int e = 0; e < NEXP; ++e) {
    const float4* wr4 = (const float4*)(srw + e * DDIM + l * 16);
    float acc = 0.f;
#pragma unroll
    for (int i = 0; i < 4; ++i) {
      float4 w4 = wr4[i];
      acc += xv[i].x * w4.x + xv[i].y * w4.y + xv[i].z * w4.z + xv[i].w * w4.w;
    }
#pragma unroll
    for (int off = 32; off > 0; off >>= 1) acc += __shfl_xor(acc, off);
    logit[e] = acc;
  }
  if (l == 0) {
    int i1 = 0;
    float v1 = logit[0];
#pragma unroll
    for (int e = 1; e < NEXP; ++e)
      if (logit[e] > v1) { v1 = logit[e]; i1 = e; }
    int i2 = -1;
    float v2 = -1e30f;
#pragma unroll
    for (int e = 0; e < NEXP; ++e)
      if (e != i1 && logit[e] > v2) { v2 = logit[e]; i2 = e; }
    float ex = expf(v2 - v1);  // v2 <= v1
    float denom = 1.f + ex;
    tok_e[2 * t] = i1;
    tok_e[2 * t + 1] = i2;
    tok_w[2 * t] = 1.f / denom;
    tok_w[2 * t + 1] = ex / denom;
    atomicAdd(&meta[i1], 1);
    atomicAdd(&meta[i2], 1);
  }
}

// ---- offsets: 256-padded segments + block->expert table --------------------
__global__ void offsets_kernel(int* meta) {
  __shared__ int seg[NEXP + 1];
  int l = threadIdx.x;
  if (l == 0) {
    int s = 0;
    for (int e = 0; e < NEXP; ++e) {
      seg[e] = s;
      meta[16 + e] = s;
      meta[8 + e] = s;  // fill cursor starts at segment base
      s += (meta[e] + 255) & ~255;
    }
    seg[NEXP] = s;
    meta[16 + NEXP] = s;
  }
  __syncthreads();
  for (int b = l; b < MAXB1; b += 64) {
    int row = b * 256, ee = -1;
#pragma unroll
    for (int e = 0; e < NEXP; ++e)
      if (row >= seg[e] && row < seg[e + 1]) ee = e;
    meta[32 + b] = ee;
  }
}

// ---- gather: pair -> slot; also inverse map pair -> position ---------------
__global__ void gather_kernel(const int* __restrict__ tok_e, int* meta,
                              int* __restrict__ row_map, int* __restrict__ inv_pos) {
  int p = blockIdx.x * 256 + threadIdx.x;  // 0..16383
  int e = tok_e[p];
  int pos = atomicAdd(&meta[8 + e], 1);
  row_map[pos] = p >> 1;
  inv_pos[p] = pos;
}

// ---- Xg fill: gather x rows as fp16 (zeros for pads) -----------------------
__global__ void xg_fill_kernel(const float* __restrict__ x,
                               const int* __restrict__ row_map,
                               _Float16* __restrict__ Xg) {
  int r = blockIdx.x, t = threadIdx.x;
  int n = row_map[r];
  half8 h = {0, 0, 0, 0, 0, 0, 0, 0};
  if (n >= 0) {
    const float4* s = (const float4*)(x + (size_t)n * DDIM + t * 8);
    float4 a = s[0], b = s[1];
    h[0] = (_Float16)a.x; h[1] = (_Float16)a.y;
    h[2] = (_Float16)a.z; h[3] = (_Float16)a.w;
    h[4] = (_Float16)b.x; h[5] = (_Float16)b.y;
    h[6] = (_Float16)b.z; h[7] = (_Float16)b.w;
  }
  *(half8*)(Xg + (size_t)r * DDIM + t * 8) = h;
}

// ---- grouped GEMM, BMx256xBK64, 8 waves, dbuf + counted vmcnt + swizzle ----
// MF = m-frags per wave (8 -> BM=256, 4 -> BM=128). Wave grid 2M x 4N.
// LDS layout per half: rows of 64 fp16 (128 B); byte-within-row XOR-swizzled
// by ((row&7)<<4) on BOTH stage (inverse-swizzled global src) and ds_read.
// Pipeline per K-tile t (buf = t&1):
//   ds_read frags (m ping-pong) -> lgkmcnt(0) -> s_barrier
//   -> STAGE(t+2 -> buf)  [overwrites fully-consumed buffer]
//   -> last m-group MFMA  [hides stage issue]
//   -> vmcnt(L) [tile t+1 landed; t+2 stays in flight] -> s_barrier.
template <int MF, int EPI>
__global__ __launch_bounds__(512, 2) void gemm256(
    const _Float16* __restrict__ A, const _Float16* __restrict__ Bbase,
    const int* __restrict__ be, int bshift, int lyt,
    size_t lda, size_t ldb, int nt, long long b_estride,
    _Float16* __restrict__ Hout, int ldh, float* __restrict__ Yout, int accum) {
  constexpr int BM = MF * 32;
  // bijective XCD-chunked swizzle, y-fastest within chunk
  int o = blockIdx.x, nb = gridDim.x;
  int q = nb >> 3, r8 = nb & 7, xc = o & 7, oo = o >> 3;
  int wg = (xc < r8 ? xc * (q + 1) : r8 * (q + 1) + (xc - r8) * q) + oo;
  int by = wg & ((1 << lyt) - 1);
  int bx = wg >> lyt;

  int e = be[bx >> bshift];
  if (e < 0) return;

  __shared__ __align__(16) _Float16 sA[2][BM * 64];
  __shared__ __align__(16) _Float16 sB[2][256 * 64];

  const _Float16* Ab = A + (size_t)bx * BM * lda;
  const _Float16* Bb = Bbase + (size_t)e * b_estride + (size_t)by * 256 * ldb;

  int tid = threadIdx.x;
  int l = tid & 63, wid = tid >> 6;
  int wm = wid >> 2, wn = wid & 3;
  int rbA = wm * (MF * 16) + (l & 15);
  int cbB = wn * 64 + (l & 15);
  int sw = (l & 7) << 4;
  int ko0 = (((l >> 4) << 4) ^ sw) >> 1;         // fp16 elems, kk=0
  int ko1 = ((64 + ((l >> 4) << 4)) ^ sw) >> 1;  // kk=1

  // stage constants: thread covers LDS bytes (tid*16 + i*8192); row=(tid>>3)+64i
  int srow = tid >> 3;
  int scol = ((((tid & 7) << 4) ^ ((srow & 7) << 4)) >> 1);  // swizzled src col

  floatx4 acc[MF][4] = {};

  auto STAGE = [&](int t, int bsel) {
    const _Float16* As = Ab + (size_t)t * 64;
    const _Float16* Bs = Bb + (size_t)t * 64;
#pragma unroll
    for (int i = 0; i < MF / 2; ++i)
      gload_lds16(As + (size_t)(srow + 64 * i) * lda + scol,
                  (void*)(&sA[bsel][(tid + 512 * i) * 8]));
#pragma unroll
    for (int i = 0; i < 4; ++i)
      gload_lds16(Bs + (size_t)(srow + 64 * i) * ldb + scol,
                  (void*)(&sB[bsel][(tid + 512 * i) * 8]));
  };

  auto BODY = [&](int t, int bsel) {
    const _Float16* sAb = sA[bsel];
    const _Float16* sBb = sB[bsel];
    half8 bf0[4], bf1[4];
#pragma unroll
    for (int n = 0; n < 4; ++n) {
      bf0[n] = *(const half8*)&sBb[(cbB + n * 16) * 64 + ko0];
      bf1[n] = *(const half8*)&sBb[(cbB + n * 16) * 64 + ko1];
    }
    __builtin_amdgcn_s_setprio(1);
    half8 aP0 = *(const half8*)&sAb[rbA * 64 + ko0];
    half8 aP1 = *(const half8*)&sAb[rbA * 64 + ko1];
    half8 aQ0, aQ1;
#pragma unroll
    for (int m = 0; m < MF - 1; ++m) {
      if ((m & 1) == 0) {
        aQ0 = *(const half8*)&sAb[(rbA + (m + 1) * 16) * 64 + ko0];
        aQ1 = *(const half8*)&sAb[(rbA + (m + 1) * 16) * 64 + ko1];
#pragma unroll
        for (int n = 0; n < 4; ++n)
          acc[m][n] = __builtin_amdgcn_mfma_f32_16x16x32_f16(aP0, bf0[n], acc[m][n], 0, 0, 0);
#pragma unroll
        for (int n = 0; n < 4; ++n)
          acc[m][n] = __builtin_amdgcn_mfma_f32_16x16x32_f16(aP1, bf1[n], acc[m][n], 0, 0, 0);
      } else {
        aP0 = *(const half8*)&sAb[(rbA + (m + 1) * 16) * 64 + ko0];
        aP1 = *(const half8*)&sAb[(rbA + (m + 1) * 16) * 64 + ko1];
#pragma unroll
        for (int n = 0; n < 4; ++n)
          acc[m][n] = __builtin_amdgcn_mfma_f32_16x16x32_f16(aQ0, bf0[n], acc[m][n], 0, 0, 0);
#pragma unroll
        for (int n = 0; n < 4; ++n)
          acc[m][n] = __builtin_amdgcn_mfma_f32_16x16x32_f16(aQ1, bf1[n], acc[m][n], 0, 0, 0);
      }
    }
    LGKM0;                           // all my ds_reads data-complete
    __builtin_amdgcn_s_barrier();    // everyone done reading this buf
    if (t + 2 < nt) STAGE(t + 2, bsel);
    // last m-group (frags sit in aQ since MF-2 is even)
#pragma unroll
    for (int n = 0; n < 4; ++n)
      acc[MF - 1][n] = __builtin_amdgcn_mfma_f32_16x16x32_f16(aQ0, bf0[n], acc[MF - 1][n], 0, 0, 0);
#pragma unroll
    for (int n = 0; n < 4; ++n)
      acc[MF - 1][n] = __builtin_amdgcn_mfma_f32_16x16x32_f16(aQ1, bf1[n], acc[MF - 1][n], 0, 0, 0);
    __builtin_amdgcn_s_setprio(0);
    if (t + 2 < nt) {
      if constexpr (MF == 8) { VMCNT(8); } else { VMCNT(6); }  // t+1 landed
      __builtin_amdgcn_s_barrier();
    } else if (t + 1 < nt) {
      VMCNT(0);
      __builtin_amdgcn_s_barrier();
    }
  };

  STAGE(0, 0);
  STAGE(1, 1);
  if constexpr (MF == 8) { VMCNT(8); } else { VMCNT(6); }  // tile0 landed
  __builtin_amdgcn_s_barrier();
  for (int tt = 0; tt < nt; tt += 2) {
    BODY(tt, 0);
    BODY(tt + 1, 1);
  }

  if (EPI == 0) {
#pragma unroll
    for (int m = 0; m < MF; ++m) {
#pragma unroll
      for (int j = 0; j < 4; ++j) {
        size_t r = (size_t)bx * BM + wm * (MF * 16) + m * 16 + (l >> 4) * 4 + j;
        _Float16* hp = Hout + r * ldh + (size_t)by * 256 + wn * 64 + (l & 15);
#pragma unroll
        for (int n = 0; n < 4; ++n) hp[n * 16] = (_Float16)gelu_fast(acc[m][n][j]);
      }
    }
  } else {
#pragma unroll
    for (int m = 0; m < MF; ++m) {
#pragma unroll
      for (int j = 0; j < 4; ++j) {
        size_t r = (size_t)bx * BM + wm * (MF * 16) + m * 16 + (l >> 4) * 4 + j;
        float* yp = Yout + r * DDIM + (size_t)by * 256 + wn * 64 + (l & 15);
        if (accum) {
#pragma unroll
          for (int n = 0; n < 4; ++n) yp[n * 16] += acc[m][n][j];
        } else {
#pragma unroll
          for (int n = 0; n < 4; ++n) yp[n * 16] = acc[m][n][j];
        }
      }
    }
  }
}

// ---- combine: out[t] = w0 * Y[pos0] + w1 * Y[pos1] -------------------------
__global__ __launch_bounds__(128) void combine_kernel(
    const float* __restrict__ Y, const int* __restrict__ inv_pos,
    const float* __restrict__ tok_w, float* __restrict__ out) {
  int t = blockIdx.x, l = threadIdx.x;
  int p0 = inv_pos[2 * t], p1 = inv_pos[2 * t + 1];
  float w0 = tok_w[2 * t], w1 = tok_w[2 * t + 1];
  const float4* y0 = (const float4*)(Y + (size_t)p0 * DDIM) + l * 2;
  const float4* y1 = (const float4*)(Y + (size_t)p1 * DDIM) + l * 2;
  float4* o = (float4*)(out + (size_t)t * DDIM) + l * 2;
#pragma unroll
  for (int i = 0; i < 2; ++i) {
    float4 a = y0[i], b = y1[i];
    float4 r;
    r.x = w0 * a.x + w1 * b.x;
    r.y = w0 * a.y + w1 * b.y;
    r.z = w0 * a.z + w1 * b.z;
    r.w = w0 * a.w + w1 * b.w;
    o[i] = r;
  }
}

// ---------------- launch -----------------------------------------------------
extern "C" void kernel_launch(void* const* d_in, const int* in_sizes, int n_in,
                              void* d_out, int out_size, void* d_ws, size_t ws_size,
                              hipStream_t stream) {
  const float* x = (const float*)d_in[0];
  const float* rw = (const float*)d_in[1];
  const float* w1 = (const float*)d_in[2];
  const float* w2 = (const float*)d_in[3];
  float* out = (float*)d_out;

  char* base = (char*)d_ws;
  size_t off = 0;
  auto alloc = [&](size_t bytes) {
    void* p = base + off;
    off += (bytes + 255) & ~(size_t)255;
    return p;
  };
  _Float16* w1t = (_Float16*)alloc((size_t)NEXP * FDIM * DDIM * 2);
  _Float16* w2t = (_Float16*)alloc((size_t)NEXP * DDIM * FDIM * 2);
  _Float16* Xg = (_Float16*)alloc((size_t)MAX_ROWS * DDIM * 2);
  float* Y = (float*)alloc((size_t)MAX_ROWS * DDIM * 4);
  int* row_map = (int*)alloc(MAX_ROWS * 4);
  int* inv_pos = (int*)alloc(N_TOK * 2 * 4);
  int* tok_e = (int*)alloc(N_TOK * 2 * 4);
  float* tok_w = (float*)alloc(N_TOK * 2 * 4);
  int* meta = (int*)alloc(1024);
  size_t fixed = off;

  // F-chunking so the H buffer fits the provided workspace. Fc >= 256 always.
  int NC = 1;
  while (NC < 16 && fixed + (size_t)MAX_ROWS * (FDIM / NC) * 2 > ws_size) NC *= 2;
  int Fc = FDIM / NC;
  _Float16* H = (_Float16*)alloc((size_t)MAX_ROWS * Fc * 2);

  hipMemsetAsync(meta, 0, 64, stream);                  // counts + fill
  hipMemsetAsync(row_map, 0xFF, MAX_ROWS * 4, stream);  // -1 sentinels

  conv_transpose<<<dim3(FDIM / 64, DDIM / 64, NEXP), 256, 0, stream>>>(w1, w1t, DDIM, FDIM);
  conv_transpose<<<dim3(DDIM / 64, FDIM / 64, NEXP), 256, 0, stream>>>(w2, w2t, FDIM, DDIM);
  router_kernel<<<N_TOK / 4, 256, 0, stream>>>(x, rw, tok_e, tok_w, meta);
  offsets_kernel<<<1, 64, 0, stream>>>(meta);
  gather_kernel<<<N_TOK * 2 / 256, 256, 0, stream>>>(tok_e, meta, row_map, inv_pos);
  xg_fill_kernel<<<MAX_ROWS, 128, 0, stream>>>(x, row_map, Xg);

  const int* be = meta + 32;
  int yt1 = Fc / 256;                        // power of two (1..16)
  int ly1 = 31 - __builtin_clz(yt1);
  for (int c = 0; c < NC; ++c) {
    // GEMM1: Xg[M,1024] x w1t[e][Fc,1024]^T -> gelu -> H[M,Fc]   (BM=256)
    gemm256<8, 0><<<dim3(MAXB1 * yt1), 512, 0, stream>>>(
        Xg, w1t + (size_t)c * Fc * DDIM, be, 0, ly1,
        (size_t)DDIM, (size_t)DDIM, DDIM / 64, (long long)FDIM * DDIM,
        H, Fc, nullptr, 0);
    // GEMM2: H[M,Fc] x w2t[e][1024,FDIM(slice c)]^T -> Y[M,1024]  (BM=128)
    gemm256<4, 1><<<dim3(MAXB1 * 2 * 4), 512, 0, stream>>>(
        H, w2t + (size_t)c * Fc, be, 1, 2,
        (size_t)Fc, (size_t)FDIM, Fc / 64, (long long)DDIM * FDIM,
        nullptr, 0, Y, c > 0);
  }
  combine_kernel<<<N_TOK, 128, 0, stream>>>(Y, inv_pos, tok_w, out);
}